// Round 2
// baseline (505.456 us; speedup 1.0000x reference)
//
#include <hip/hip_runtime.h>
#include <hip/hip_bf16.h>
#include <math.h>

#define DEMB 64
#define NPBKT 256          // nodes per coarse bucket (c >> 8)
#define CHUNK 4096         // edges per binning workgroup
#define MAXBKT 512
#define SENT_CAP 7168      // LDS staging entries in pass B (57 KB)

typedef float v2f __attribute__((ext_vector_type(2)));
typedef short short8 __attribute__((ext_vector_type(8)));
typedef float f32x4 __attribute__((ext_vector_type(4)));

// ---------------- helpers ----------------

__device__ __forceinline__ float rdlane(float v, int k) {
    return __int_as_float(__builtin_amdgcn_readlane(__float_as_int(v), k));
}
__device__ __forceinline__ unsigned int f2bf(float f) {
    union { float f; unsigned int i; } c; c.f = f;
    unsigned int r = c.i + 0x7FFFu + ((c.i >> 16) & 1u);   // RNE
    return r >> 16;
}

// pack 64 lanes' y (feature=lane) into fp8 row; lanes 0..15 store one dword each
__device__ __forceinline__ void pack_store_fp8(float y, unsigned int* __restrict__ dst, int lane) {
    float y0 = __shfl(y, 4 * lane + 0);
    float y1 = __shfl(y, 4 * lane + 1);
    float y2 = __shfl(y, 4 * lane + 2);
    float y3 = __shfl(y, 4 * lane + 3);
    int u = __builtin_amdgcn_cvt_pk_fp8_f32(y0, y1, 0, false);
    u = __builtin_amdgcn_cvt_pk_fp8_f32(y2, y3, u, true);
    if (lane < 16) dst[lane] = (unsigned int)u;
}

// ---------------- preprocessing: zero-atomic exact-base counting sort ----------------

__global__ __launch_bounds__(256) void histA_kernel(const int* __restrict__ ei,
                                                    int* __restrict__ histM,
                                                    int E, int NBKT) {
    __shared__ int lh[MAXBKT];
    int t = threadIdx.x;
    for (int b = t; b < MAXBKT; b += 256) lh[b] = 0;
    __syncthreads();
    int base = blockIdx.x * CHUNK;
    int end = base + CHUNK; if (end > E) end = E;
    for (int i = base + t; i < end; i += 256)
        atomicAdd(&lh[((unsigned int)ei[E + i]) >> 8], 1);
    __syncthreads();
    for (int b = t; b < NBKT; b += 256) {
        int c = lh[b];
        histM[(size_t)blockIdx.x * NBKT + b] = c ? ((c + 7) & ~7) : 0;
    }
}

__global__ __launch_bounds__(256) void scanM_kernel(int* __restrict__ histM,
                                                    int* __restrict__ bktcnt,
                                                    int NWG, int NBKT) {
    int b = blockIdx.x;
    int t = threadIdx.x, lane = t & 63, w = t >> 6;
    int w0 = 2 * t, w1 = 2 * t + 1;
    int v0 = (w0 < NWG) ? histM[(size_t)w0 * NBKT + b] : 0;
    int v1 = (w1 < NWG) ? histM[(size_t)w1 * NBKT + b] : 0;
    int s = v0 + v1;
    int sc = s;
    #pragma unroll
    for (int off = 1; off < 64; off <<= 1) {
        int u = __shfl_up(sc, off);
        if (lane >= off) sc += u;
    }
    __shared__ int wt[4];
    if (lane == 63) wt[w] = sc;
    __syncthreads();
    int woff = 0;
    for (int i = 0; i < w; i++) woff += wt[i];
    int ex = woff + sc - s;
    if (w0 < NWG) histM[(size_t)w0 * NBKT + b] = ex;
    if (w1 < NWG) histM[(size_t)w1 * NBKT + b] = ex + v0;
    if (t == 0) bktcnt[b] = wt[0] + wt[1] + wt[2] + wt[3];
}

__global__ void scanB_kernel(const int* __restrict__ bktcnt, int* __restrict__ bktbase,
                             int NBKT) {
    __shared__ int sh[512];
    int t = threadIdx.x;
    int mine = (t < NBKT) ? bktcnt[t] : 0;
    sh[t] = mine;
    __syncthreads();
    for (int off = 1; off < 512; off <<= 1) {
        int v = (t >= off) ? sh[t - off] : 0;
        __syncthreads();
        sh[t] += v;
        __syncthreads();
    }
    if (t < NBKT) bktbase[t] = sh[t] - mine;
    if (t == 511) bktbase[NBKT] = sh[511];
}

// entry: x = (c&255)<<20 | r  (valid x >= 0), sentinel pad x = -1
__global__ __launch_bounds__(256) void binA_kernel(const int* __restrict__ ei,
                                                   const float* __restrict__ ew,
                                                   const int* __restrict__ histM,
                                                   const int* __restrict__ bktbase,
                                                   int2* __restrict__ cells,
                                                   int E, int NBKT) {
    __shared__ int lh[MAXBKT];
    __shared__ int lbs[MAXBKT];
    __shared__ int lcur[MAXBKT];
    int t = threadIdx.x;
    for (int b = t; b < MAXBKT; b += 256) { lh[b] = 0; lcur[b] = 0; }
    __syncthreads();
    int base = blockIdx.x * CHUNK;
    int end = base + CHUNK; if (end > E) end = E;

    int cc[CHUNK / 256];
    int nloc = 0;
    for (int i = base + t; i < end; i += 256, nloc++) {
        int c = ei[E + i];
        cc[nloc] = c;
        atomicAdd(&lh[((unsigned int)c) >> 8], 1);
    }
    __syncthreads();
    for (int b = t; b < NBKT; b += 256)
        lbs[b] = bktbase[b] + histM[(size_t)blockIdx.x * NBKT + b];
    __syncthreads();
    int k = 0;
    for (int i = base + t; i < end; i += 256, k++) {
        unsigned int c = (unsigned int)cc[k];
        unsigned int r = (unsigned int)ei[i];
        int wbits = __float_as_int(ew[i]);
        int bkt = c >> 8;
        int rel = atomicAdd(&lcur[bkt], 1);
        cells[lbs[bkt] + rel] = make_int2((int)(((c & 255u) << 20) | r), wbits);
    }
    __syncthreads();
    for (int b = t; b < NBKT; b += 256) {
        int cnt = lh[b];
        if (cnt) {
            int pc = (cnt + 7) & ~7;
            for (int j = cnt; j < pc; j++)
                cells[lbs[b] + j] = make_int2(-1, 0);
        }
    }
}

// pass B: per bucket — count + weighted degree (skip sentinels), 8-quantum padded scan,
// write dis/rowse (padded ends), sort into LDS with (self,0) row pads, stream CSR out.
__global__ __launch_bounds__(256) void bucketB_kernel(
    const int2* __restrict__ cells, const int* __restrict__ bktbase,
    int2* __restrict__ csr, int2* __restrict__ rowse, float* __restrict__ dis, int N) {
    __shared__ int scnt[NPBKT];
    __shared__ float sdeg[NPBKT];
    __shared__ int sstart[NPBKT];
    __shared__ int sfill[NPBKT];
    __shared__ int ssc[NPBKT];
    __shared__ int2 sout[SENT_CAP];

    int b = blockIdx.x;
    int t = threadIdx.x;
    int nodebase = b << 8;
    int nNodes = N - nodebase; if (nNodes > NPBKT) nNodes = NPBKT;

    if (t < NPBKT) { scnt[t] = 0; sdeg[t] = 1.0f; sfill[t] = 0; }   // self-loop deg=1
    __syncthreads();

    int lo = bktbase[b], hi = bktbase[b + 1];
    int outbase = lo + b * (NPBKT * 7);     // room for row pads, disjoint per bucket

    for (int i = lo + t; i < hi; i += 256) {
        int2 en = cells[i];
        if (en.x >= 0) {
            unsigned int ld = ((unsigned int)en.x) >> 20;
            atomicAdd(&scnt[ld], 1);
            atomicAdd(&sdeg[ld], __int_as_float(en.y));
        }
    }
    __syncthreads();

    int cnt_t = scnt[t];
    int pc_t = (cnt_t + 7) & ~7;            // padded row length
    ssc[t] = pc_t;
    __syncthreads();
    for (int off = 1; off < NPBKT; off <<= 1) {
        int v = (t >= off) ? ssc[t - off] : 0;
        __syncthreads();
        ssc[t] += v;
        __syncthreads();
    }
    sstart[t] = ssc[t] - pc_t;
    __syncthreads();
    int ptotal = ssc[NPBKT - 1];

    if (t < nNodes) {
        int node = nodebase + t;
        dis[node] = rsqrtf(sdeg[t]);
        rowse[node] = make_int2(outbase + sstart[t], outbase + sstart[t] + pc_t);
    }

    if (ptotal <= SENT_CAP) {
        for (int i = lo + t; i < hi; i += 256) {
            int2 en = cells[i];
            if (en.x >= 0) {
                unsigned int ux = (unsigned int)en.x;
                unsigned int ld = ux >> 20;
                int pos = sstart[ld] + atomicAdd(&sfill[ld], 1);
                sout[pos] = make_int2((int)(ux & 0xFFFFFu), en.y);
            }
        }
        __syncthreads();
        if (t < nNodes) {
            for (int j = cnt_t; j < pc_t; j++)
                sout[sstart[t] + j] = make_int2(nodebase + t, 0);   // (self, w=0) pad
        }
        __syncthreads();
        for (int i = t; i < ptotal; i += 256)
            csr[outbase + i] = sout[i];
    } else {
        // pathological-skew fallback: direct global scatter
        for (int i = lo + t; i < hi; i += 256) {
            int2 en = cells[i];
            if (en.x >= 0) {
                unsigned int ux = (unsigned int)en.x;
                unsigned int ld = ux >> 20;
                int pos = atomicAdd(&sfill[ld], 1);
                csr[outbase + sstart[ld] + pos] = make_int2((int)(ux & 0xFFFFFu), en.y);
            }
        }
        __syncthreads();
        if (t < nNodes) {
            for (int j = cnt_t; j < pc_t; j++)
                csr[outbase + sstart[t] + j] = make_int2(nodebase + t, 0);
        }
    }
}

// ---------------- encoder: stores s = dis * h_enc as fp8 ----------------

__global__ __launch_bounds__(256, 4) void encoder_kernel(
    const float* __restrict__ x, const float* __restrict__ dis,
    const float* __restrict__ w1, const float* __restrict__ b1,
    const float* __restrict__ w2, const float* __restrict__ b2,
    unsigned int* __restrict__ hout4, int N) {
    int lane = threadIdx.x & 63;
    int wid = __builtin_amdgcn_readfirstlane((blockIdx.x * blockDim.x + threadIdx.x) >> 6);
    int n0 = wid * 4;
    if (n0 >= N) return;

    float w2col[DEMB];
    #pragma unroll
    for (int k = 0; k < DEMB; k++) w2col[k] = w2[k * DEMB + lane];
    float w1a = w1[lane], w1b = w1[DEMB + lane];
    float b1v = b1[lane], b2v = b2[lane];

    float xv = 0.0f;
    if (lane < 8 && n0 * 2 + lane < 2 * N) xv = x[n0 * 2 + lane];

    #pragma unroll
    for (int m = 0; m < 4; m++) {
        int node = n0 + m;
        if (node >= N) continue;
        float x0 = rdlane(xv, 2 * m);
        float x1 = rdlane(xv, 2 * m + 1);
        float t = fmaxf(0.0f, fmaf(x0, w1a, fmaf(x1, w1b, b1v)));
        float y = b2v;
        #pragma unroll
        for (int k = 0; k < DEMB; k++)
            y = fmaf(rdlane(t, k), w2col[k], y);
        pack_store_fp8(y * dis[node], hout4 + (size_t)node * 16, lane);
    }
}

// ------- fused layer, wave-independent: W preloaded to LDS in MFMA-frag layout once
// per block (single barrier at top), then each wave runs agg(2 nodes) -> in-register
// shuffle into MFMA A-fragment -> 8 MFMA (B-frags from LDS) -> fp8 pack -> store,
// with NO further cross-wave synchronization. LAST adds decoder reading only its own
// wave's h' rows from LDS (wave-internal ordering only).
// agg lane map: lane = m*32 + p*4 + q  (m=node, p=edge slot, q=feature 16-block)
// MFMA A layout (verified by working transform kernel): lane l holds
//   A[l&15][kt*32 + (l>>4)*8 + j]; after the p-reduce every lane holds the full
//   16-feature block for its (m, q), so feature f of node m lives at lane m*32+ (f>>4)
//   reg ((f&15)>>1) comp (f&1)  ->  src lane = (l&1)*32 + kt*2 + ((l>>4)>>1).

__device__ __forceinline__ void agg_acc8(v2f* __restrict__ acc, uint4 u, float w) {
    v2f wv = {w, w};
    acc[0] += wv * __builtin_amdgcn_cvt_pk_f32_fp8((int)u.x, false);
    acc[1] += wv * __builtin_amdgcn_cvt_pk_f32_fp8((int)u.x, true);
    acc[2] += wv * __builtin_amdgcn_cvt_pk_f32_fp8((int)u.y, false);
    acc[3] += wv * __builtin_amdgcn_cvt_pk_f32_fp8((int)u.y, true);
    acc[4] += wv * __builtin_amdgcn_cvt_pk_f32_fp8((int)u.z, false);
    acc[5] += wv * __builtin_amdgcn_cvt_pk_f32_fp8((int)u.z, true);
    acc[6] += wv * __builtin_amdgcn_cvt_pk_f32_fp8((int)u.w, false);
    acc[7] += wv * __builtin_amdgcn_cvt_pk_f32_fp8((int)u.w, true);
}

template<int LAST>
__global__ __launch_bounds__(512, LAST ? 4 : 8) void fused_layer_kernel(
    const uint4* __restrict__ hin4, const int2* __restrict__ csr,
    const int2* __restrict__ rowse, const float* __restrict__ dis,
    const float* __restrict__ W, const float* __restrict__ bias,
    unsigned char* __restrict__ hout8,
    const float* __restrict__ x,
    const float* __restrict__ dw1, const float* __restrict__ db1,
    const float* __restrict__ dw2, const float* __restrict__ db2,
    float* __restrict__ out, int N) {

    __shared__ short Wl[8][64][8];                    // [nt*2+kt][lane][j] bf16, 8 KB
    __shared__ unsigned char h8l[LAST ? 1024 : 4];    // 16 rows x 64 fp8 (LAST only)

    int t = threadIdx.x;
    int lane = t & 63;
    int wl = __builtin_amdgcn_readfirstlane(t >> 6);  // 0..7
    int tilebase = blockIdx.x * 16;
    int n0 = tilebase + wl * 2;

    // ---- W preload: bf16 fragments, cooperative, the only barrier ----
    {
        int g = t >> 6, ln = t & 63;                  // g = nt*2+kt
        int nt = g >> 1, kt = g & 1;
        int col = ln & 15, quad = ln >> 4;
        short8 wf;
        #pragma unroll
        for (int j = 0; j < 8; j++)
            wf[j] = (short)f2bf(W[(kt * 32 + quad * 8 + j) * DEMB + nt * 16 + col]);
        *(short8*)(&Wl[g][ln][0]) = wf;
    }
    __syncthreads();
    if (n0 >= N) return;

    // ---- phase 1: aggregation (identical math to previous rounds) ----
    int m = lane >> 5;
    int p = (lane >> 2) & 7;
    int q = lane & 3;
    int node = n0 + m;
    bool valid = node < N;
    int cn = valid ? node : (N - 1);

    uint4 su = hin4[(size_t)cn * 4 + q];
    v2f acc[8];
    float sw = (p == 0) ? 1.0f : 0.0f;
    v2f swv = {sw, sw};
    acc[0] = swv * __builtin_amdgcn_cvt_pk_f32_fp8((int)su.x, false);
    acc[1] = swv * __builtin_amdgcn_cvt_pk_f32_fp8((int)su.x, true);
    acc[2] = swv * __builtin_amdgcn_cvt_pk_f32_fp8((int)su.y, false);
    acc[3] = swv * __builtin_amdgcn_cvt_pk_f32_fp8((int)su.y, true);
    acc[4] = swv * __builtin_amdgcn_cvt_pk_f32_fp8((int)su.z, false);
    acc[5] = swv * __builtin_amdgcn_cvt_pk_f32_fp8((int)su.z, true);
    acc[6] = swv * __builtin_amdgcn_cvt_pk_f32_fp8((int)su.w, false);
    acc[7] = swv * __builtin_amdgcn_cvt_pk_f32_fp8((int)su.w, true);

    int2 se = rowse[cn];
    int s = se.x, e = se.y;                 // padded to multiple of 8
    for (int i = s; i < e; i += 16) {
        int2 eA = csr[i + p];               // broadcast over 4 q-lanes
        uint4 uA = hin4[(size_t)eA.x * 4 + q];
        if (i + 8 < e) {
            int2 eB = csr[i + 8 + p];
            uint4 uB = hin4[(size_t)eB.x * 4 + q];
            agg_acc8(acc, uA, __int_as_float(eA.y));
            agg_acc8(acc, uB, __int_as_float(eB.y));
        } else {
            agg_acc8(acc, uA, __int_as_float(eA.y));
        }
    }

    // reduce over p (lane bits 2..4): xor 4, 8, 16 — all lanes end with full sum
    #pragma unroll
    for (int off = 4; off <= 16; off <<= 1) {
        #pragma unroll
        for (int k = 0; k < 8; k++) {
            acc[k].x += __shfl_xor(acc[k].x, off);
            acc[k].y += __shfl_xor(acc[k].y, off);
        }
    }

    // G row = dis * sum (scale in-register; same FP ops as before)
    float d = dis[cn];
    v2f dv = {d, d};
    #pragma unroll
    for (int k = 0; k < 8; k++) acc[k] *= dv;

    // ---- phase 2: shuffle accumulator into MFMA A-fragments (bf16) ----
    int col = lane & 15, quad = lane >> 4;
    int s0 = ((lane & 1) << 5) + (quad >> 1);   // src for Af0 (k < 32)
    int s1 = s0 + 2;                            // src for Af1 (k >= 32)
    bool hiHalf = (quad & 1) != 0;
    short8 Af0, Af1;
    #pragma unroll
    for (int j = 0; j < 8; j++) {
        float v0lo = __shfl((j & 1) ? acc[(j >> 1)].y : acc[(j >> 1)].x, s0);
        float v0hi = __shfl((j & 1) ? acc[4 + (j >> 1)].y : acc[4 + (j >> 1)].x, s0);
        float v1lo = __shfl((j & 1) ? acc[(j >> 1)].y : acc[(j >> 1)].x, s1);
        float v1hi = __shfl((j & 1) ? acc[4 + (j >> 1)].y : acc[4 + (j >> 1)].x, s1);
        Af0[j] = (short)f2bf(hiHalf ? v0hi : v0lo);
        Af1[j] = (short)f2bf(hiHalf ? v1hi : v1lo);
    }

    // ---- phase 3: 8 MFMA + epilogue; rows 0,1 of C are our 2 nodes ----
    float d0 = rdlane(d, 0);                    // dis[node0]
    float d1 = rdlane(d, 32);                   // dis[node1]
    bool valid0 = n0 < N, valid1 = (n0 + 1) < N;

    #pragma unroll
    for (int nt = 0; nt < 4; nt++) {
        short8 B0 = *(const short8*)(&Wl[nt * 2 + 0][lane][0]);
        short8 B1 = *(const short8*)(&Wl[nt * 2 + 1][lane][0]);
        f32x4 z = {0.0f, 0.0f, 0.0f, 0.0f};
        z = __builtin_amdgcn_mfma_f32_16x16x32_bf16(Af0, B0, z, 0, 0, 0);
        z = __builtin_amdgcn_mfma_f32_16x16x32_bf16(Af1, B1, z, 0, 0, 0);
        float bv = bias[nt * 16 + col];
        // C layout: col = lane&15, row = (lane>>4)*4 + reg -> rows 0,1 in quad 0
        float y0 = fmaxf(z[0] + bv, 0.0f) * (LAST ? 1.0f : d0);
        float y1 = fmaxf(z[1] + bv, 0.0f) * (LAST ? 1.0f : d1);
        // lanes 0..3 pack dword `lane` (cols 4*lane .. 4*lane+3) per node
        float a0 = __shfl(y0, 4 * lane + 0), a1 = __shfl(y0, 4 * lane + 1);
        float a2 = __shfl(y0, 4 * lane + 2), a3 = __shfl(y0, 4 * lane + 3);
        int u0 = __builtin_amdgcn_cvt_pk_fp8_f32(a0, a1, 0, false);
        u0 = __builtin_amdgcn_cvt_pk_fp8_f32(a2, a3, u0, true);
        float b0 = __shfl(y1, 4 * lane + 0), b1 = __shfl(y1, 4 * lane + 1);
        float b2 = __shfl(y1, 4 * lane + 2), b3 = __shfl(y1, 4 * lane + 3);
        int u1 = __builtin_amdgcn_cvt_pk_fp8_f32(b0, b1, 0, false);
        u1 = __builtin_amdgcn_cvt_pk_fp8_f32(b2, b3, u1, true);
        if (LAST) {
            if (lane < 4) {
                *(unsigned int*)(&h8l[(wl * 2 + 0) * 64 + nt * 16 + lane * 4]) = (unsigned int)u0;
                *(unsigned int*)(&h8l[(wl * 2 + 1) * 64 + nt * 16 + lane * 4]) = (unsigned int)u1;
            }
        } else {
            if (lane < 4 && valid0)
                ((unsigned int*)(hout8 + (size_t)n0 * DEMB + nt * 16))[lane] = (unsigned int)u0;
            if (lane < 4 && valid1)
                ((unsigned int*)(hout8 + (size_t)(n0 + 1) * DEMB + nt * 16))[lane] = (unsigned int)u1;
        }
    }

    // ---- phase 4 (LAST only): fp32 decoder + softmax + residual, wave-local ----
    if (LAST) {
        float w1col[DEMB];
        #pragma unroll
        for (int k = 0; k < DEMB; k++) w1col[k] = dw1[k * DEMB + lane];
        float db1v = db1[lane];
        float w20 = dw2[lane * 2], w21 = dw2[lane * 2 + 1];
        float db20 = db2[0], db21 = db2[1];

        float xv = 0.0f;
        if (lane < 4 && n0 * 2 + lane < 2 * N) xv = x[n0 * 2 + lane];

        float myout = 0.0f;
        #pragma unroll
        for (int mm = 0; mm < 2; mm++) {
            int nd = n0 + mm;
            if (nd >= N) continue;
            float hv = __builtin_amdgcn_cvt_f32_fp8((int)h8l[(wl * 2 + mm) * 64 + lane], 0);
            float yv = db1v;
            #pragma unroll
            for (int k = 0; k < DEMB; k++)
                yv = fmaf(rdlane(hv, k), w1col[k], yv);
            float d1v = fmaxf(yv, 0.0f);
            float p0 = d1v * w20, p1 = d1v * w21;
            #pragma unroll
            for (int off = 32; off > 0; off >>= 1) {
                p0 += __shfl_xor(p0, off);
                p1 += __shfl_xor(p1, off);
            }
            float o0 = p0 + db20, o1 = p1 + db21;
            float mx = fmaxf(o0, o1);
            float e0 = __expf(o0 - mx), e1 = __expf(o1 - mx);
            float inv = 1.0f / (e0 + e1);
            float r0 = e0 * inv + 2.0f * rdlane(xv, 2 * mm);   // wc = [2, 0]
            float r1 = e1 * inv;
            if (lane == 2 * mm) myout = r0;
            if (lane == 2 * mm + 1) myout = r1;
        }
        if (lane < 4 && n0 * 2 + lane < 2 * N)
            out[n0 * 2 + lane] = myout;
    }
}

// ---------------- launch ----------------

extern "C" void kernel_launch(void* const* d_in, const int* in_sizes, int n_in,
                              void* d_out, int out_size, void* d_ws, size_t ws_size,
                              hipStream_t stream) {
    const float* x      = (const float*)d_in[0];
    const int*   ei     = (const int*)d_in[1];
    const float* ew     = (const float*)d_in[2];
    const float* enc_w1 = (const float*)d_in[3];
    const float* enc_b1 = (const float*)d_in[4];
    const float* enc_w2 = (const float*)d_in[5];
    const float* enc_b2 = (const float*)d_in[6];
    const float* gcn_w  = (const float*)d_in[7];
    const float* gcn_b  = (const float*)d_in[8];
    const float* dec_w1 = (const float*)d_in[9];
    const float* dec_b1 = (const float*)d_in[10];
    const float* dec_w2 = (const float*)d_in[11];
    const float* dec_b2 = (const float*)d_in[12];
    float* out = (float*)d_out;

    const int N = in_sizes[0] / 2;
    const int E = in_sizes[2];
    const int L = in_sizes[7] / (DEMB * DEMB);
    const int NBKT = (N + NPBKT - 1) / NPBKT;
    const int NWG = (E + CHUNK - 1) / CHUNK;

    size_t padcap = (size_t)E + (size_t)NWG * NBKT * 7 + 64;          // cells
    size_t csrcap = padcap + (size_t)NBKT * NPBKT * 7;                // + row pads

    // workspace layout (256B aligned); h rows 64 B fp8
    char* ws = (char*)d_ws;
    size_t o = 0;
    auto alignup = [](size_t v) { return (v + 255) & ~(size_t)255; };
    unsigned int* hA = (unsigned int*)(ws + o); o = alignup(o + (size_t)N * DEMB);
    unsigned int* hB = (unsigned int*)(ws + o); o = alignup(o + (size_t)N * DEMB);
    float* dis     = (float*)(ws + o); o = alignup(o + (size_t)N * 4);
    int2*  rowse   = (int2*)(ws + o);  o = alignup(o + (size_t)N * 8);
    int*   histM   = (int*)(ws + o);   o = alignup(o + (size_t)NWG * NBKT * 4);
    int*   bktcnt  = (int*)(ws + o);   o = alignup(o + (size_t)MAXBKT * 4);
    int*   bktbase = (int*)(ws + o);   o = alignup(o + (size_t)(MAXBKT + 1) * 4);
    size_t cells_bytes = padcap * 8;
    int2*  cells   = (int2*)(ws + o);  o = alignup(o + cells_bytes);
    int2*  csr     = (int2*)(ws + o);  o = alignup(o + csrcap * 8);

    const int TB = 256;
    dim3 blk(TB);
    dim3 blk512(512);
    dim3 gWave4((N * 16 + TB - 1) / TB);          // wave per 4 nodes (encoder)
    dim3 gFused((N + 15) / 16);                   // 16 nodes per 512-thread block

    histA_kernel<<<NWG, blk, 0, stream>>>(ei, histM, E, NBKT);
    scanM_kernel<<<NBKT, blk, 0, stream>>>(histM, bktcnt, NWG, NBKT);
    scanB_kernel<<<1, 512, 0, stream>>>(bktcnt, bktbase, NBKT);
    binA_kernel<<<NWG, blk, 0, stream>>>(ei, ew, histM, bktbase, cells, E, NBKT);
    bucketB_kernel<<<NBKT, blk, 0, stream>>>(cells, bktbase, csr, rowse, dis, N);

    encoder_kernel<<<gWave4, blk, 0, stream>>>(x, dis, enc_w1, enc_b1, enc_w2, enc_b2, hA, N);

    unsigned int* hin = hA;
    unsigned int* hout = hB;
    for (int l = 0; l < L; l++) {
        const float* Wl = gcn_w + (size_t)l * DEMB * DEMB;
        const float* bl = gcn_b + (size_t)l * DEMB;
        if (l < L - 1) {
            fused_layer_kernel<0><<<gFused, blk512, 0, stream>>>(
                (const uint4*)hin, csr, rowse, dis, Wl, bl,
                (unsigned char*)hout, nullptr,
                nullptr, nullptr, nullptr, nullptr, nullptr, N);
            unsigned int* t = hin; hin = hout; hout = t;
        } else {
            fused_layer_kernel<1><<<gFused, blk512, 0, stream>>>(
                (const uint4*)hin, csr, rowse, dis, Wl, bl,
                nullptr, x, dec_w1, dec_b1, dec_w2, dec_b2, out, N);
        }
    }
}

// Round 3
// 393.070 us; speedup vs baseline: 1.2859x; 1.2859x over previous
//
#include <hip/hip_runtime.h>
#include <hip/hip_bf16.h>
#include <math.h>

#define DEMB 64
#define NPBKT 256          // nodes per coarse bucket (c >> 8)
#define CHUNK 4096         // edges per binning workgroup
#define MAXBKT 512
#define SENT_CAP 7168      // LDS staging entries in pass B (57 KB)

typedef float v2f __attribute__((ext_vector_type(2)));
typedef short short8 __attribute__((ext_vector_type(8)));
typedef float f32x4 __attribute__((ext_vector_type(4)));

// ---------------- helpers ----------------

__device__ __forceinline__ float rdlane(float v, int k) {
    return __int_as_float(__builtin_amdgcn_readlane(__float_as_int(v), k));
}
__device__ __forceinline__ unsigned int f2bf(float f) {
    union { float f; unsigned int i; } c; c.f = f;
    unsigned int r = c.i + 0x7FFFu + ((c.i >> 16) & 1u);   // RNE
    return r >> 16;
}

// pack 64 lanes' y (feature=lane) into fp8 row; lanes 0..15 store one dword each
__device__ __forceinline__ void pack_store_fp8(float y, unsigned int* __restrict__ dst, int lane) {
    float y0 = __shfl(y, 4 * lane + 0);
    float y1 = __shfl(y, 4 * lane + 1);
    float y2 = __shfl(y, 4 * lane + 2);
    float y3 = __shfl(y, 4 * lane + 3);
    int u = __builtin_amdgcn_cvt_pk_fp8_f32(y0, y1, 0, false);
    u = __builtin_amdgcn_cvt_pk_fp8_f32(y2, y3, u, true);
    if (lane < 16) dst[lane] = (unsigned int)u;
}

// ---------------- preprocessing: zero-atomic exact-base counting sort ----------------

__global__ __launch_bounds__(256) void histA_kernel(const int* __restrict__ ei,
                                                    int* __restrict__ histM,
                                                    int E, int NBKT) {
    __shared__ int lh[MAXBKT];
    int t = threadIdx.x;
    for (int b = t; b < MAXBKT; b += 256) lh[b] = 0;
    __syncthreads();
    int base = blockIdx.x * CHUNK;
    int end = base + CHUNK; if (end > E) end = E;
    for (int i = base + t; i < end; i += 256)
        atomicAdd(&lh[((unsigned int)ei[E + i]) >> 8], 1);
    __syncthreads();
    for (int b = t; b < NBKT; b += 256) {
        int c = lh[b];
        histM[(size_t)blockIdx.x * NBKT + b] = c ? ((c + 7) & ~7) : 0;
    }
}

__global__ __launch_bounds__(256) void scanM_kernel(int* __restrict__ histM,
                                                    int* __restrict__ bktcnt,
                                                    int NWG, int NBKT) {
    int b = blockIdx.x;
    int t = threadIdx.x, lane = t & 63, w = t >> 6;
    int w0 = 2 * t, w1 = 2 * t + 1;
    int v0 = (w0 < NWG) ? histM[(size_t)w0 * NBKT + b] : 0;
    int v1 = (w1 < NWG) ? histM[(size_t)w1 * NBKT + b] : 0;
    int s = v0 + v1;
    int sc = s;
    #pragma unroll
    for (int off = 1; off < 64; off <<= 1) {
        int u = __shfl_up(sc, off);
        if (lane >= off) sc += u;
    }
    __shared__ int wt[4];
    if (lane == 63) wt[w] = sc;
    __syncthreads();
    int woff = 0;
    for (int i = 0; i < w; i++) woff += wt[i];
    int ex = woff + sc - s;
    if (w0 < NWG) histM[(size_t)w0 * NBKT + b] = ex;
    if (w1 < NWG) histM[(size_t)w1 * NBKT + b] = ex + v0;
    if (t == 0) bktcnt[b] = wt[0] + wt[1] + wt[2] + wt[3];
}

__global__ void scanB_kernel(const int* __restrict__ bktcnt, int* __restrict__ bktbase,
                             int NBKT) {
    __shared__ int sh[512];
    int t = threadIdx.x;
    int mine = (t < NBKT) ? bktcnt[t] : 0;
    sh[t] = mine;
    __syncthreads();
    for (int off = 1; off < 512; off <<= 1) {
        int v = (t >= off) ? sh[t - off] : 0;
        __syncthreads();
        sh[t] += v;
        __syncthreads();
    }
    if (t < NBKT) bktbase[t] = sh[t] - mine;
    if (t == 511) bktbase[NBKT] = sh[511];
}

// entry: x = (c&255)<<20 | r  (valid x >= 0), sentinel pad x = -1
__global__ __launch_bounds__(256) void binA_kernel(const int* __restrict__ ei,
                                                   const float* __restrict__ ew,
                                                   const int* __restrict__ histM,
                                                   const int* __restrict__ bktbase,
                                                   int2* __restrict__ cells,
                                                   int E, int NBKT) {
    __shared__ int lh[MAXBKT];
    __shared__ int lbs[MAXBKT];
    __shared__ int lcur[MAXBKT];
    int t = threadIdx.x;
    for (int b = t; b < MAXBKT; b += 256) { lh[b] = 0; lcur[b] = 0; }
    __syncthreads();
    int base = blockIdx.x * CHUNK;
    int end = base + CHUNK; if (end > E) end = E;

    int cc[CHUNK / 256];
    int nloc = 0;
    for (int i = base + t; i < end; i += 256, nloc++) {
        int c = ei[E + i];
        cc[nloc] = c;
        atomicAdd(&lh[((unsigned int)c) >> 8], 1);
    }
    __syncthreads();
    for (int b = t; b < NBKT; b += 256)
        lbs[b] = bktbase[b] + histM[(size_t)blockIdx.x * NBKT + b];
    __syncthreads();
    int k = 0;
    for (int i = base + t; i < end; i += 256, k++) {
        unsigned int c = (unsigned int)cc[k];
        unsigned int r = (unsigned int)ei[i];
        int wbits = __float_as_int(ew[i]);
        int bkt = c >> 8;
        int rel = atomicAdd(&lcur[bkt], 1);
        cells[lbs[bkt] + rel] = make_int2((int)(((c & 255u) << 20) | r), wbits);
    }
    __syncthreads();
    for (int b = t; b < NBKT; b += 256) {
        int cnt = lh[b];
        if (cnt) {
            int pc = (cnt + 7) & ~7;
            for (int j = cnt; j < pc; j++)
                cells[lbs[b] + j] = make_int2(-1, 0);
        }
    }
}

// pass B: per bucket — count + weighted degree (skip sentinels), 8-quantum padded scan,
// write dis/rowse (padded ends), sort into LDS with (self,0) row pads, stream CSR out.
__global__ __launch_bounds__(256) void bucketB_kernel(
    const int2* __restrict__ cells, const int* __restrict__ bktbase,
    int2* __restrict__ csr, int2* __restrict__ rowse, float* __restrict__ dis, int N) {
    __shared__ int scnt[NPBKT];
    __shared__ float sdeg[NPBKT];
    __shared__ int sstart[NPBKT];
    __shared__ int sfill[NPBKT];
    __shared__ int ssc[NPBKT];
    __shared__ int2 sout[SENT_CAP];

    int b = blockIdx.x;
    int t = threadIdx.x;
    int nodebase = b << 8;
    int nNodes = N - nodebase; if (nNodes > NPBKT) nNodes = NPBKT;

    if (t < NPBKT) { scnt[t] = 0; sdeg[t] = 1.0f; sfill[t] = 0; }   // self-loop deg=1
    __syncthreads();

    int lo = bktbase[b], hi = bktbase[b + 1];
    int outbase = lo + b * (NPBKT * 7);     // room for row pads, disjoint per bucket

    for (int i = lo + t; i < hi; i += 256) {
        int2 en = cells[i];
        if (en.x >= 0) {
            unsigned int ld = ((unsigned int)en.x) >> 20;
            atomicAdd(&scnt[ld], 1);
            atomicAdd(&sdeg[ld], __int_as_float(en.y));
        }
    }
    __syncthreads();

    int cnt_t = scnt[t];
    int pc_t = (cnt_t + 7) & ~7;            // padded row length
    ssc[t] = pc_t;
    __syncthreads();
    for (int off = 1; off < NPBKT; off <<= 1) {
        int v = (t >= off) ? ssc[t - off] : 0;
        __syncthreads();
        ssc[t] += v;
        __syncthreads();
    }
    sstart[t] = ssc[t] - pc_t;
    __syncthreads();
    int ptotal = ssc[NPBKT - 1];

    if (t < nNodes) {
        int node = nodebase + t;
        dis[node] = rsqrtf(sdeg[t]);
        rowse[node] = make_int2(outbase + sstart[t], outbase + sstart[t] + pc_t);
    }

    if (ptotal <= SENT_CAP) {
        for (int i = lo + t; i < hi; i += 256) {
            int2 en = cells[i];
            if (en.x >= 0) {
                unsigned int ux = (unsigned int)en.x;
                unsigned int ld = ux >> 20;
                int pos = sstart[ld] + atomicAdd(&sfill[ld], 1);
                sout[pos] = make_int2((int)(ux & 0xFFFFFu), en.y);
            }
        }
        __syncthreads();
        if (t < nNodes) {
            for (int j = cnt_t; j < pc_t; j++)
                sout[sstart[t] + j] = make_int2(nodebase + t, 0);   // (self, w=0) pad
        }
        __syncthreads();
        for (int i = t; i < ptotal; i += 256)
            csr[outbase + i] = sout[i];
    } else {
        // pathological-skew fallback: direct global scatter
        for (int i = lo + t; i < hi; i += 256) {
            int2 en = cells[i];
            if (en.x >= 0) {
                unsigned int ux = (unsigned int)en.x;
                unsigned int ld = ux >> 20;
                int pos = atomicAdd(&sfill[ld], 1);
                csr[outbase + sstart[ld] + pos] = make_int2((int)(ux & 0xFFFFFu), en.y);
            }
        }
        __syncthreads();
        if (t < nNodes) {
            for (int j = cnt_t; j < pc_t; j++)
                csr[outbase + sstart[t] + j] = make_int2(nodebase + t, 0);
        }
    }
}

// ---------------- encoder: stores s = dis * h_enc as fp8 ----------------

__global__ __launch_bounds__(256, 4) void encoder_kernel(
    const float* __restrict__ x, const float* __restrict__ dis,
    const float* __restrict__ w1, const float* __restrict__ b1,
    const float* __restrict__ w2, const float* __restrict__ b2,
    unsigned int* __restrict__ hout4, int N) {
    int lane = threadIdx.x & 63;
    int wid = __builtin_amdgcn_readfirstlane((blockIdx.x * blockDim.x + threadIdx.x) >> 6);
    int n0 = wid * 4;
    if (n0 >= N) return;

    float w2col[DEMB];
    #pragma unroll
    for (int k = 0; k < DEMB; k++) w2col[k] = w2[k * DEMB + lane];
    float w1a = w1[lane], w1b = w1[DEMB + lane];
    float b1v = b1[lane], b2v = b2[lane];

    float xv = 0.0f;
    if (lane < 8 && n0 * 2 + lane < 2 * N) xv = x[n0 * 2 + lane];

    #pragma unroll
    for (int m = 0; m < 4; m++) {
        int node = n0 + m;
        if (node >= N) continue;
        float x0 = rdlane(xv, 2 * m);
        float x1 = rdlane(xv, 2 * m + 1);
        float t = fmaxf(0.0f, fmaf(x0, w1a, fmaf(x1, w1b, b1v)));
        float y = b2v;
        #pragma unroll
        for (int k = 0; k < DEMB; k++)
            y = fmaf(rdlane(t, k), w2col[k], y);
        pack_store_fp8(y * dis[node], hout4 + (size_t)node * 16, lane);
    }
}

// ------- fused layer (round-1 structure + W-LDS preload + 3-deep gather pipeline) ---
// Block = 256 thr = 4 waves = 8-node tile. Phases:
//   0. cooperative W preload -> LDS frag layout (coalesced global reads), barrier
//   1. per-wave agg of 2 nodes (lane = m*32 + p*4 + q), 3-deep clamped gather loop
//   2. p-reduce, bf16 pack, Gl LDS staging (swizzled), barrier
//   3. per-wave MFMA: nt = wl (16 output cols), B-frags from Wl, A-frags from Gl
//   4. fp8 epilogue (byte stores); LAST: wave-local decoder + softmax + residual

__device__ __forceinline__ void agg_acc8(v2f* __restrict__ acc, uint4 u, float w) {
    v2f wv = {w, w};
    acc[0] += wv * __builtin_amdgcn_cvt_pk_f32_fp8((int)u.x, false);
    acc[1] += wv * __builtin_amdgcn_cvt_pk_f32_fp8((int)u.x, true);
    acc[2] += wv * __builtin_amdgcn_cvt_pk_f32_fp8((int)u.y, false);
    acc[3] += wv * __builtin_amdgcn_cvt_pk_f32_fp8((int)u.y, true);
    acc[4] += wv * __builtin_amdgcn_cvt_pk_f32_fp8((int)u.z, false);
    acc[5] += wv * __builtin_amdgcn_cvt_pk_f32_fp8((int)u.z, true);
    acc[6] += wv * __builtin_amdgcn_cvt_pk_f32_fp8((int)u.w, false);
    acc[7] += wv * __builtin_amdgcn_cvt_pk_f32_fp8((int)u.w, true);
}

template<int LAST>
__global__ __launch_bounds__(256, LAST ? 4 : 8) void fused_layer_kernel(
    const uint4* __restrict__ hin4, const int2* __restrict__ csr,
    const int2* __restrict__ rowse, const float* __restrict__ dis,
    const float* __restrict__ W, const float* __restrict__ bias,
    unsigned char* __restrict__ hout8,
    const float* __restrict__ x,
    const float* __restrict__ dw1, const float* __restrict__ db1,
    const float* __restrict__ dw2, const float* __restrict__ db2,
    float* __restrict__ out, int N) {

    __shared__ short Wl[8][64][8];                   // [nt*2+kt][quad*16+col][j], 8 KB
    __shared__ uint4 Gl[64];                         // 8 rows x 128 B bf16, swizzled
    __shared__ unsigned char h8l[LAST ? 512 : 4];    // fp8 h' tile (LAST only)

    int t = threadIdx.x;
    int lane = t & 63;
    int wl = __builtin_amdgcn_readfirstlane(t >> 6);   // 0..3
    int tilebase = blockIdx.x * 8;
    int n0 = tilebase + wl * 2;

    // ---- phase 0: W preload, coalesced reads / scattered LDS stores ----
    #pragma unroll
    for (int rr = 0; rr < 16; rr++) {
        int li = rr * 256 + t;                       // linear index into W
        int r = li >> 6, c = li & 63;
        int nt = c >> 4, col = c & 15, kt = r >> 5, quad = (r >> 3) & 3, j = r & 7;
        Wl[nt * 2 + kt][quad * 16 + col][j] = (short)f2bf(W[li]);
    }
    __syncthreads();

    // ---- phase 1: aggregation, 3-deep clamped gather pipeline ----
    int m = lane >> 5;
    int p = (lane >> 2) & 7;
    int q = lane & 3;
    int node = n0 + m;
    bool valid = node < N;
    int cn = valid ? node : (N - 1);

    uint4 su = hin4[(size_t)cn * 4 + q];
    v2f acc[8];
    float sw = (p == 0) ? 1.0f : 0.0f;
    v2f swv = {sw, sw};
    acc[0] = swv * __builtin_amdgcn_cvt_pk_f32_fp8((int)su.x, false);
    acc[1] = swv * __builtin_amdgcn_cvt_pk_f32_fp8((int)su.x, true);
    acc[2] = swv * __builtin_amdgcn_cvt_pk_f32_fp8((int)su.y, false);
    acc[3] = swv * __builtin_amdgcn_cvt_pk_f32_fp8((int)su.y, true);
    acc[4] = swv * __builtin_amdgcn_cvt_pk_f32_fp8((int)su.z, false);
    acc[5] = swv * __builtin_amdgcn_cvt_pk_f32_fp8((int)su.z, true);
    acc[6] = swv * __builtin_amdgcn_cvt_pk_f32_fp8((int)su.w, false);
    acc[7] = swv * __builtin_amdgcn_cvt_pk_f32_fp8((int)su.w, true);

    int2 se = rowse[cn];
    int s = se.x, e = se.y;                 // padded to multiple of 8, >= 8
    for (int i = s; i < e; i += 24) {
        bool g1 = (i + 8) < e;              // uniform per 32-lane half
        bool g2 = (i + 16) < e;
        int a1 = g1 ? (i + 8) : s;          // clamp to a guaranteed-valid group
        int a2 = g2 ? (i + 16) : s;
        int2 e0 = csr[i + p];
        int2 e1 = csr[a1 + p];
        int2 e2 = csr[a2 + p];
        uint4 u0 = hin4[(size_t)e0.x * 4 + q];
        uint4 u1 = hin4[(size_t)e1.x * 4 + q];
        uint4 u2 = hin4[(size_t)e2.x * 4 + q];
        agg_acc8(acc, u0, __int_as_float(e0.y));
        agg_acc8(acc, u1, g1 ? __int_as_float(e1.y) : 0.0f);
        agg_acc8(acc, u2, g2 ? __int_as_float(e2.y) : 0.0f);
    }

    // reduce over p (lane bits 2..4): xor 4, 8, 16
    #pragma unroll
    for (int off = 4; off <= 16; off <<= 1) {
        #pragma unroll
        for (int k = 0; k < 8; k++) {
            acc[k].x += __shfl_xor(acc[k].x, off);
            acc[k].y += __shfl_xor(acc[k].y, off);
        }
    }

    float d = dis[cn];
    if (p == 0 && valid) {
        int nl = node - tilebase;           // 0..7
        uint4 g0, g1;
        g0.x = f2bf(acc[0].x * d) | (f2bf(acc[0].y * d) << 16);
        g0.y = f2bf(acc[1].x * d) | (f2bf(acc[1].y * d) << 16);
        g0.z = f2bf(acc[2].x * d) | (f2bf(acc[2].y * d) << 16);
        g0.w = f2bf(acc[3].x * d) | (f2bf(acc[3].y * d) << 16);
        g1.x = f2bf(acc[4].x * d) | (f2bf(acc[4].y * d) << 16);
        g1.y = f2bf(acc[5].x * d) | (f2bf(acc[5].y * d) << 16);
        g1.z = f2bf(acc[6].x * d) | (f2bf(acc[6].y * d) << 16);
        g1.w = f2bf(acc[7].x * d) | (f2bf(acc[7].y * d) << 16);
        char* gb = (char*)Gl;
        int swz = (nl & 7) << 4;
        *(uint4*)(gb + nl * 128 + ((q * 32) ^ swz)) = g0;       // features q*16..+7
        *(uint4*)(gb + nl * 128 + ((q * 32 + 16) ^ swz)) = g1;  // features q*16+8..+15
    }
    __syncthreads();

    // ---- phase 3: transform  h' = relu(G·W + b) (* dis unless LAST) -> fp8 ----
    int col = lane & 15, quad = lane >> 4;
    int nt = wl;                            // each wave: 16 output cols
    short8 Bf0 = *(const short8*)(&Wl[nt * 2 + 0][lane][0]);
    short8 Bf1 = *(const short8*)(&Wl[nt * 2 + 1][lane][0]);
    float bv = bias[nt * 16 + col];

    int r = col & 7;                        // rows 8..15 duplicate 0..7, discarded
    const char* gb = (const char*)Gl;
    short8 Af0 = *(const short8*)(gb + r * 128 + ((quad * 16) ^ (r << 4)));
    short8 Af1 = *(const short8*)(gb + r * 128 + ((64 + quad * 16) ^ (r << 4)));

    f32x4 z = {0.0f, 0.0f, 0.0f, 0.0f};
    z = __builtin_amdgcn_mfma_f32_16x16x32_bf16(Af0, Bf0, z, 0, 0, 0);
    z = __builtin_amdgcn_mfma_f32_16x16x32_bf16(Af1, Bf1, z, 0, 0, 0);

    #pragma unroll
    for (int reg = 0; reg < 4; reg++) {
        int nr = quad * 4 + reg;            // C row = node-local index
        if (nr < 8) {
            int nd = tilebase + nr;
            if (nd < N) {
                float os = LAST ? 1.0f : dis[nd];
                float y = fmaxf(z[reg] + bv, 0.0f) * os;
                int u = __builtin_amdgcn_cvt_pk_fp8_f32(y, y, 0, false);
                if (LAST) h8l[nr * 64 + nt * 16 + col] = (unsigned char)(u & 0xff);
                else hout8[(size_t)nd * 64 + nt * 16 + col] = (unsigned char)(u & 0xff);
            }
        }
    }

    // ---- phase 4 (LAST only): fp32 decoder + softmax + residual ----
    if (LAST) {
        __syncthreads();
        float w1col[DEMB];
        #pragma unroll
        for (int k = 0; k < DEMB; k++) w1col[k] = dw1[k * DEMB + lane];
        float db1v = db1[lane];
        float w20 = dw2[lane * 2], w21 = dw2[lane * 2 + 1];
        float db20 = db2[0], db21 = db2[1];

        float xv = 0.0f;
        if (lane < 4 && n0 * 2 + lane < 2 * N) xv = x[n0 * 2 + lane];

        float myout = 0.0f;
        #pragma unroll
        for (int mm = 0; mm < 2; mm++) {
            int nd = n0 + mm;
            if (nd >= N) continue;
            int nl = nd - tilebase;
            float hv = __builtin_amdgcn_cvt_f32_fp8((int)h8l[nl * 64 + lane], 0);
            float yv = db1v;
            #pragma unroll
            for (int k = 0; k < DEMB; k++)
                yv = fmaf(rdlane(hv, k), w1col[k], yv);
            float d1v = fmaxf(yv, 0.0f);
            float p0 = d1v * w20, p1 = d1v * w21;
            #pragma unroll
            for (int off = 32; off > 0; off >>= 1) {
                p0 += __shfl_xor(p0, off);
                p1 += __shfl_xor(p1, off);
            }
            float o0 = p0 + db20, o1 = p1 + db21;
            float mx = fmaxf(o0, o1);
            float e0 = __expf(o0 - mx), e1 = __expf(o1 - mx);
            float inv = 1.0f / (e0 + e1);
            float r0 = e0 * inv + 2.0f * rdlane(xv, 2 * mm);   // wc = [2, 0]
            float r1 = e1 * inv;
            if (lane == 2 * mm) myout = r0;
            if (lane == 2 * mm + 1) myout = r1;
        }
        if (lane < 4 && n0 * 2 + lane < 2 * N)
            out[n0 * 2 + lane] = myout;
    }
}

// ---------------- launch ----------------

extern "C" void kernel_launch(void* const* d_in, const int* in_sizes, int n_in,
                              void* d_out, int out_size, void* d_ws, size_t ws_size,
                              hipStream_t stream) {
    const float* x      = (const float*)d_in[0];
    const int*   ei     = (const int*)d_in[1];
    const float* ew     = (const float*)d_in[2];
    const float* enc_w1 = (const float*)d_in[3];
    const float* enc_b1 = (const float*)d_in[4];
    const float* enc_w2 = (const float*)d_in[5];
    const float* enc_b2 = (const float*)d_in[6];
    const float* gcn_w  = (const float*)d_in[7];
    const float* gcn_b  = (const float*)d_in[8];
    const float* dec_w1 = (const float*)d_in[9];
    const float* dec_b1 = (const float*)d_in[10];
    const float* dec_w2 = (const float*)d_in[11];
    const float* dec_b2 = (const float*)d_in[12];
    float* out = (float*)d_out;

    const int N = in_sizes[0] / 2;
    const int E = in_sizes[2];
    const int L = in_sizes[7] / (DEMB * DEMB);
    const int NBKT = (N + NPBKT - 1) / NPBKT;
    const int NWG = (E + CHUNK - 1) / CHUNK;

    size_t padcap = (size_t)E + (size_t)NWG * NBKT * 7 + 64;          // cells
    size_t csrcap = padcap + (size_t)NBKT * NPBKT * 7;                // + row pads

    // workspace layout (256B aligned); h rows 64 B fp8
    char* ws = (char*)d_ws;
    size_t o = 0;
    auto alignup = [](size_t v) { return (v + 255) & ~(size_t)255; };
    unsigned int* hA = (unsigned int*)(ws + o); o = alignup(o + (size_t)N * DEMB);
    unsigned int* hB = (unsigned int*)(ws + o); o = alignup(o + (size_t)N * DEMB);
    float* dis     = (float*)(ws + o); o = alignup(o + (size_t)N * 4);
    int2*  rowse   = (int2*)(ws + o);  o = alignup(o + (size_t)N * 8);
    int*   histM   = (int*)(ws + o);   o = alignup(o + (size_t)NWG * NBKT * 4);
    int*   bktcnt  = (int*)(ws + o);   o = alignup(o + (size_t)MAXBKT * 4);
    int*   bktbase = (int*)(ws + o);   o = alignup(o + (size_t)(MAXBKT + 1) * 4);
    size_t cells_bytes = padcap * 8;
    int2*  cells   = (int2*)(ws + o);  o = alignup(o + cells_bytes);
    int2*  csr     = (int2*)(ws + o);  o = alignup(o + csrcap * 8);

    const int TB = 256;
    dim3 blk(TB);
    dim3 gWave4((N * 16 + TB - 1) / TB);          // wave per 4 nodes (encoder)
    dim3 gFused((N + 7) / 8);                     // 8 nodes per 256-thread block

    histA_kernel<<<NWG, blk, 0, stream>>>(ei, histM, E, NBKT);
    scanM_kernel<<<NBKT, blk, 0, stream>>>(histM, bktcnt, NWG, NBKT);
    scanB_kernel<<<1, 512, 0, stream>>>(bktcnt, bktbase, NBKT);
    binA_kernel<<<NWG, blk, 0, stream>>>(ei, ew, histM, bktbase, cells, E, NBKT);
    bucketB_kernel<<<NBKT, blk, 0, stream>>>(cells, bktbase, csr, rowse, dis, N);

    encoder_kernel<<<gWave4, blk, 0, stream>>>(x, dis, enc_w1, enc_b1, enc_w2, enc_b2, hA, N);

    unsigned int* hin = hA;
    unsigned int* hout = hB;
    for (int l = 0; l < L; l++) {
        const float* Wl = gcn_w + (size_t)l * DEMB * DEMB;
        const float* bl = gcn_b + (size_t)l * DEMB;
        if (l < L - 1) {
            fused_layer_kernel<0><<<gFused, blk, 0, stream>>>(
                (const uint4*)hin, csr, rowse, dis, Wl, bl,
                (unsigned char*)hout, nullptr,
                nullptr, nullptr, nullptr, nullptr, nullptr, N);
            unsigned int* t = hin; hin = hout; hout = t;
        } else {
            fused_layer_kernel<1><<<gFused, blk, 0, stream>>>(
                (const uint4*)hin, csr, rowse, dis, Wl, bl,
                nullptr, x, dec_w1, dec_b1, dec_w2, dec_b2, out, N);
        }
    }
}

// Round 4
// 367.147 us; speedup vs baseline: 1.3767x; 1.0706x over previous
//
#include <hip/hip_runtime.h>
#include <hip/hip_bf16.h>
#include <math.h>

#define DEMB 64
#define NPBKT 256          // nodes per coarse bucket (c >> 8)
#define CHUNK 4096         // edges per binning workgroup
#define MAXBKT 512
#define SENT_CAP 7168      // LDS staging entries in pass B (57 KB)

typedef float v2f __attribute__((ext_vector_type(2)));
typedef short short8 __attribute__((ext_vector_type(8)));
typedef float f32x4 __attribute__((ext_vector_type(4)));

// ---------------- helpers ----------------

__device__ __forceinline__ float rdlane(float v, int k) {
    return __int_as_float(__builtin_amdgcn_readlane(__float_as_int(v), k));
}
__device__ __forceinline__ unsigned int f2bf(float f) {
    union { float f; unsigned int i; } c; c.f = f;
    unsigned int r = c.i + 0x7FFFu + ((c.i >> 16) & 1u);   // RNE
    return r >> 16;
}

// pack 64 lanes' y (feature=lane) into fp8 row; lanes 0..15 store one dword each
__device__ __forceinline__ void pack_store_fp8(float y, unsigned int* __restrict__ dst, int lane) {
    float y0 = __shfl(y, 4 * lane + 0);
    float y1 = __shfl(y, 4 * lane + 1);
    float y2 = __shfl(y, 4 * lane + 2);
    float y3 = __shfl(y, 4 * lane + 3);
    int u = __builtin_amdgcn_cvt_pk_fp8_f32(y0, y1, 0, false);
    u = __builtin_amdgcn_cvt_pk_fp8_f32(y2, y3, u, true);
    if (lane < 16) dst[lane] = (unsigned int)u;
}

// ---------------- preprocessing: zero-atomic exact-base counting sort ----------------

__global__ __launch_bounds__(256) void histA_kernel(const int* __restrict__ ei,
                                                    int* __restrict__ histM,
                                                    int E, int NBKT) {
    __shared__ int lh[MAXBKT];
    int t = threadIdx.x;
    for (int b = t; b < MAXBKT; b += 256) lh[b] = 0;
    __syncthreads();
    int base = blockIdx.x * CHUNK;
    int end = base + CHUNK; if (end > E) end = E;
    for (int i = base + t; i < end; i += 256)
        atomicAdd(&lh[((unsigned int)ei[E + i]) >> 8], 1);
    __syncthreads();
    for (int b = t; b < NBKT; b += 256) {
        int c = lh[b];
        histM[(size_t)blockIdx.x * NBKT + b] = c ? ((c + 7) & ~7) : 0;
    }
}

__global__ __launch_bounds__(256) void scanM_kernel(int* __restrict__ histM,
                                                    int* __restrict__ bktcnt,
                                                    int NWG, int NBKT) {
    int b = blockIdx.x;
    int t = threadIdx.x, lane = t & 63, w = t >> 6;
    int w0 = 2 * t, w1 = 2 * t + 1;
    int v0 = (w0 < NWG) ? histM[(size_t)w0 * NBKT + b] : 0;
    int v1 = (w1 < NWG) ? histM[(size_t)w1 * NBKT + b] : 0;
    int s = v0 + v1;
    int sc = s;
    #pragma unroll
    for (int off = 1; off < 64; off <<= 1) {
        int u = __shfl_up(sc, off);
        if (lane >= off) sc += u;
    }
    __shared__ int wt[4];
    if (lane == 63) wt[w] = sc;
    __syncthreads();
    int woff = 0;
    for (int i = 0; i < w; i++) woff += wt[i];
    int ex = woff + sc - s;
    if (w0 < NWG) histM[(size_t)w0 * NBKT + b] = ex;
    if (w1 < NWG) histM[(size_t)w1 * NBKT + b] = ex + v0;
    if (t == 0) bktcnt[b] = wt[0] + wt[1] + wt[2] + wt[3];
}

__global__ void scanB_kernel(const int* __restrict__ bktcnt, int* __restrict__ bktbase,
                             int NBKT) {
    __shared__ int sh[512];
    int t = threadIdx.x;
    int mine = (t < NBKT) ? bktcnt[t] : 0;
    sh[t] = mine;
    __syncthreads();
    for (int off = 1; off < 512; off <<= 1) {
        int v = (t >= off) ? sh[t - off] : 0;
        __syncthreads();
        sh[t] += v;
        __syncthreads();
    }
    if (t < NBKT) bktbase[t] = sh[t] - mine;
    if (t == 511) bktbase[NBKT] = sh[511];
}

// entry: x = (c&255)<<20 | r  (valid x >= 0), sentinel pad x = -1
__global__ __launch_bounds__(256) void binA_kernel(const int* __restrict__ ei,
                                                   const float* __restrict__ ew,
                                                   const int* __restrict__ histM,
                                                   const int* __restrict__ bktbase,
                                                   int2* __restrict__ cells,
                                                   int E, int NBKT) {
    __shared__ int lh[MAXBKT];
    __shared__ int lbs[MAXBKT];
    __shared__ int lcur[MAXBKT];
    int t = threadIdx.x;
    for (int b = t; b < MAXBKT; b += 256) { lh[b] = 0; lcur[b] = 0; }
    __syncthreads();
    int base = blockIdx.x * CHUNK;
    int end = base + CHUNK; if (end > E) end = E;

    int cc[CHUNK / 256];
    int nloc = 0;
    for (int i = base + t; i < end; i += 256, nloc++) {
        int c = ei[E + i];
        cc[nloc] = c;
        atomicAdd(&lh[((unsigned int)c) >> 8], 1);
    }
    __syncthreads();
    for (int b = t; b < NBKT; b += 256)
        lbs[b] = bktbase[b] + histM[(size_t)blockIdx.x * NBKT + b];
    __syncthreads();
    int k = 0;
    for (int i = base + t; i < end; i += 256, k++) {
        unsigned int c = (unsigned int)cc[k];
        unsigned int r = (unsigned int)ei[i];
        int wbits = __float_as_int(ew[i]);
        int bkt = c >> 8;
        int rel = atomicAdd(&lcur[bkt], 1);
        cells[lbs[bkt] + rel] = make_int2((int)(((c & 255u) << 20) | r), wbits);
    }
    __syncthreads();
    for (int b = t; b < NBKT; b += 256) {
        int cnt = lh[b];
        if (cnt) {
            int pc = (cnt + 7) & ~7;
            for (int j = cnt; j < pc; j++)
                cells[lbs[b] + j] = make_int2(-1, 0);
        }
    }
}

// pass B: per bucket — count + weighted degree (skip sentinels), padded scan,
// write dis/rowse, sort into LDS. Rows padded to (cnt+8)&~7: the FIRST pad slot is
// (self, w=1.0) — the self-loop term — remaining pads are (self, 0).
__global__ __launch_bounds__(256) void bucketB_kernel(
    const int2* __restrict__ cells, const int* __restrict__ bktbase,
    int2* __restrict__ csr, int2* __restrict__ rowse, float* __restrict__ dis, int N) {
    __shared__ int scnt[NPBKT];
    __shared__ float sdeg[NPBKT];
    __shared__ int sstart[NPBKT];
    __shared__ int sfill[NPBKT];
    __shared__ int ssc[NPBKT];
    __shared__ int2 sout[SENT_CAP];

    int b = blockIdx.x;
    int t = threadIdx.x;
    int nodebase = b << 8;
    int nNodes = N - nodebase; if (nNodes > NPBKT) nNodes = NPBKT;

    if (t < NPBKT) { scnt[t] = 0; sdeg[t] = 1.0f; sfill[t] = 0; }   // self-loop deg=1
    __syncthreads();

    int lo = bktbase[b], hi = bktbase[b + 1];
    int outbase = lo + b * (NPBKT * 8);     // room for row pads (<=8/node), disjoint

    for (int i = lo + t; i < hi; i += 256) {
        int2 en = cells[i];
        if (en.x >= 0) {
            unsigned int ld = ((unsigned int)en.x) >> 20;
            atomicAdd(&scnt[ld], 1);
            atomicAdd(&sdeg[ld], __int_as_float(en.y));
        }
    }
    __syncthreads();

    int cnt_t = scnt[t];
    int pc_t = (cnt_t + 8) & ~7;            // padded row length (includes self slot)
    ssc[t] = pc_t;
    __syncthreads();
    for (int off = 1; off < NPBKT; off <<= 1) {
        int v = (t >= off) ? ssc[t - off] : 0;
        __syncthreads();
        ssc[t] += v;
        __syncthreads();
    }
    sstart[t] = ssc[t] - pc_t;
    __syncthreads();
    int ptotal = ssc[NPBKT - 1];

    if (t < nNodes) {
        int node = nodebase + t;
        dis[node] = rsqrtf(sdeg[t]);
        rowse[node] = make_int2(outbase + sstart[t], outbase + sstart[t] + pc_t);
    }

    if (ptotal <= SENT_CAP) {
        for (int i = lo + t; i < hi; i += 256) {
            int2 en = cells[i];
            if (en.x >= 0) {
                unsigned int ux = (unsigned int)en.x;
                unsigned int ld = ux >> 20;
                int pos = sstart[ld] + atomicAdd(&sfill[ld], 1);
                sout[pos] = make_int2((int)(ux & 0xFFFFFu), en.y);
            }
        }
        __syncthreads();
        if (t < nNodes) {
            for (int j = cnt_t; j < pc_t; j++)
                sout[sstart[t] + j] =
                    make_int2(nodebase + t, (j == cnt_t) ? 0x3f800000 : 0);
        }
        __syncthreads();
        for (int i = t; i < ptotal; i += 256)
            csr[outbase + i] = sout[i];
    } else {
        // pathological-skew fallback: direct global scatter
        for (int i = lo + t; i < hi; i += 256) {
            int2 en = cells[i];
            if (en.x >= 0) {
                unsigned int ux = (unsigned int)en.x;
                unsigned int ld = ux >> 20;
                int pos = atomicAdd(&sfill[ld], 1);
                csr[outbase + sstart[ld] + pos] = make_int2((int)(ux & 0xFFFFFu), en.y);
            }
        }
        __syncthreads();
        if (t < nNodes) {
            for (int j = cnt_t; j < pc_t; j++)
                csr[outbase + sstart[t] + j] =
                    make_int2(nodebase + t, (j == cnt_t) ? 0x3f800000 : 0);
        }
    }
}

// ---------------- encoder: stores s = dis * h_enc as fp8 ----------------

__global__ __launch_bounds__(256, 4) void encoder_kernel(
    const float* __restrict__ x, const float* __restrict__ dis,
    const float* __restrict__ w1, const float* __restrict__ b1,
    const float* __restrict__ w2, const float* __restrict__ b2,
    unsigned int* __restrict__ hout4, int N) {
    int lane = threadIdx.x & 63;
    int wid = __builtin_amdgcn_readfirstlane((blockIdx.x * blockDim.x + threadIdx.x) >> 6);
    int n0 = wid * 4;
    if (n0 >= N) return;

    float w2col[DEMB];
    #pragma unroll
    for (int k = 0; k < DEMB; k++) w2col[k] = w2[k * DEMB + lane];
    float w1a = w1[lane], w1b = w1[DEMB + lane];
    float b1v = b1[lane], b2v = b2[lane];

    float xv = 0.0f;
    if (lane < 8 && n0 * 2 + lane < 2 * N) xv = x[n0 * 2 + lane];

    #pragma unroll
    for (int m = 0; m < 4; m++) {
        int node = n0 + m;
        if (node >= N) continue;
        float x0 = rdlane(xv, 2 * m);
        float x1 = rdlane(xv, 2 * m + 1);
        float t = fmaxf(0.0f, fmaf(x0, w1a, fmaf(x1, w1b, b1v)));
        float y = b2v;
        #pragma unroll
        for (int k = 0; k < DEMB; k++)
            y = fmaf(rdlane(t, k), w2col[k], y);
        pack_store_fp8(y * dis[node], hout4 + (size_t)node * 16, lane);
    }
}

// ------- fused layer, wave16: one wave owns 16 nodes (4 lanes/node, 16B chunk/lane).
// No cross-lane reduction (lanes own disjoint features). Self term comes from CSR
// (first pad slot w=1). Per block: 4 waves = 64 nodes; W preloaded once (8 KB LDS,
// one barrier), then waves fully independent: agg loop (2 slots/node/iter, csr
// prefetched 1 iter ahead) -> bf16 G tile in per-wave LDS (swizzled) -> 8 MFMA ->
// fp8 pack via LDS bounce -> coalesced dwordx4 store.

__device__ __forceinline__ void agg_acc8(v2f* __restrict__ acc, uint4 u, float w) {
    v2f wv = {w, w};
    acc[0] += wv * __builtin_amdgcn_cvt_pk_f32_fp8((int)u.x, false);
    acc[1] += wv * __builtin_amdgcn_cvt_pk_f32_fp8((int)u.x, true);
    acc[2] += wv * __builtin_amdgcn_cvt_pk_f32_fp8((int)u.y, false);
    acc[3] += wv * __builtin_amdgcn_cvt_pk_f32_fp8((int)u.y, true);
    acc[4] += wv * __builtin_amdgcn_cvt_pk_f32_fp8((int)u.z, false);
    acc[5] += wv * __builtin_amdgcn_cvt_pk_f32_fp8((int)u.z, true);
    acc[6] += wv * __builtin_amdgcn_cvt_pk_f32_fp8((int)u.w, false);
    acc[7] += wv * __builtin_amdgcn_cvt_pk_f32_fp8((int)u.w, true);
}

template<int SCALE>
__global__ __launch_bounds__(256, 6) void fused_layer_kernel(
    const uint4* __restrict__ hin4, const int2* __restrict__ csr,
    const int2* __restrict__ rowse, const float* __restrict__ dis,
    const float* __restrict__ W, const float* __restrict__ bias,
    unsigned char* __restrict__ hout8, int N) {

    __shared__ short Wl[8][64][8];     // B-fragments [nt*2+kt][quad*16+col][j], 8 KB
    __shared__ uint4 Gl4[4][128];      // per-wave 16 x 128 B bf16 G tile, 8 KB

    int t = threadIdx.x;
    int lane = t & 63;
    int wl = __builtin_amdgcn_readfirstlane(t >> 6);   // 0..3
    int tilebase = blockIdx.x * 64 + wl * 16;

    // ---- W preload (coalesced reads, scattered 2B LDS stores); only barrier ----
    #pragma unroll
    for (int rr = 0; rr < 16; rr++) {
        int li = rr * 256 + t;                         // linear index into W
        int r = li >> 6, c = li & 63;
        int nt = c >> 4, col = c & 15, kt = r >> 5, quad = (r >> 3) & 3, j = r & 7;
        Wl[nt * 2 + kt][quad * 16 + col][j] = (short)f2bf(W[li]);
    }
    __syncthreads();
    if (tilebase >= N) return;

    // ---- phase 1: aggregation; lane = nd*4+sub, nd=node 0..15, sub=16B chunk ----
    int nd = lane >> 2, sub = lane & 3;
    int node = tilebase + nd;
    bool vn = node < N;
    int cn = vn ? node : N - 1;

    int2 se = rowse[cn];
    int mylen = vn ? (se.y - se.x) : 0;     // multiple of 8, >= 8 for valid nodes
    int maxlen = mylen;
    #pragma unroll
    for (int off = 4; off <= 32; off <<= 1)
        maxlen = max(maxlen, __shfl_xor(maxlen, off));

    v2f acc[8];
    #pragma unroll
    for (int k = 0; k < 8; k++) acc[k] = (v2f){0.0f, 0.0f};

    int2 e0 = csr[se.x];
    int2 e1 = csr[se.x + (vn ? 1 : 0)];
    for (int it = 0; it < maxlen; it += 2) {
        int i2 = it + 2, i3 = it + 3;
        int2 f0 = csr[se.x + (i2 < mylen ? i2 : 0)];   // prefetch next pair (clamped)
        int2 f1 = csr[se.x + (i3 < mylen ? i3 : 0)];
        float wA = (it < mylen) ? __int_as_float(e0.y) : 0.0f;
        float wB = (it + 1 < mylen) ? __int_as_float(e1.y) : 0.0f;
        uint4 uA = hin4[(size_t)e0.x * 4 + sub];
        uint4 uB = hin4[(size_t)e1.x * 4 + sub];
        agg_acc8(acc, uA, wA);
        agg_acc8(acc, uB, wB);
        e0 = f0; e1 = f1;
    }

    // G row = dis_c * acc  (self term already included via w=1 pad slot)
    float d = dis[cn];
    v2f dvp = {d, d};
    #pragma unroll
    for (int k = 0; k < 8; k++) acc[k] *= dvp;

    // ---- phase 2: bf16 G tile (per-wave LDS region, XOR-swizzled rows) ----
    char* gw = (char*)(&Gl4[wl][0]);
    {
        uint4 g0, g1;
        g0.x = f2bf(acc[0].x) | (f2bf(acc[0].y) << 16);
        g0.y = f2bf(acc[1].x) | (f2bf(acc[1].y) << 16);
        g0.z = f2bf(acc[2].x) | (f2bf(acc[2].y) << 16);
        g0.w = f2bf(acc[3].x) | (f2bf(acc[3].y) << 16);
        g1.x = f2bf(acc[4].x) | (f2bf(acc[4].y) << 16);
        g1.y = f2bf(acc[5].x) | (f2bf(acc[5].y) << 16);
        g1.z = f2bf(acc[6].x) | (f2bf(acc[6].y) << 16);
        g1.w = f2bf(acc[7].x) | (f2bf(acc[7].y) << 16);
        int swz = (nd & 7) << 4;
        *(uint4*)(gw + nd * 128 + ((sub * 32) ^ swz)) = g0;       // feats sub*16..+7
        *(uint4*)(gw + nd * 128 + ((sub * 32 + 16) ^ swz)) = g1;  // feats sub*16+8..+15
    }

    // ---- phase 3: 8 MFMA; all 16 C rows are our 16 nodes ----
    int col = lane & 15, quad = lane >> 4;
    int rsw = (col & 7) << 4;
    short8 Af0 = *(const short8*)(gw + col * 128 + ((quad * 16) ^ rsw));
    short8 Af1 = *(const short8*)(gw + col * 128 + ((64 + quad * 16) ^ rsw));

    float dvv = dis[min(tilebase + col, N - 1)];   // lane c (c<16) holds dis[tile+c]

    f32x4 z[4];
    #pragma unroll
    for (int nt = 0; nt < 4; nt++) {
        short8 B0 = *(const short8*)(&Wl[nt * 2 + 0][lane][0]);
        short8 B1 = *(const short8*)(&Wl[nt * 2 + 1][lane][0]);
        f32x4 zz = {0.0f, 0.0f, 0.0f, 0.0f};
        zz = __builtin_amdgcn_mfma_f32_16x16x32_bf16(Af0, B0, zz, 0, 0, 0);
        zz = __builtin_amdgcn_mfma_f32_16x16x32_bf16(Af1, B1, zz, 0, 0, 0);
        z[nt] = zz;
    }

    // ---- phase 4: epilogue  h' = relu(z + b) (* dis if SCALE) -> fp8 rows ----
    // byte tile reuses gw (same-wave DS ops are in-order; Af already in registers)
    #pragma unroll
    for (int nt = 0; nt < 4; nt++) {
        float bv = bias[nt * 16 + col];
        #pragma unroll
        for (int reg = 0; reg < 4; reg++) {
            int nr = quad * 4 + reg;                   // node-local row 0..15
            float os = SCALE ? rdlane(dvv, nr) : 1.0f;
            float y = fmaxf(z[nt][reg] + bv, 0.0f) * os;
            int u = __builtin_amdgcn_cvt_pk_fp8_f32(y, y, 0, false);
            gw[nr * 64 + nt * 16 + col] = (unsigned char)(u & 0xff);
        }
    }
    uint4 hv4 = *(const uint4*)(gw + lane * 16);       // row lane>>2, chunk lane&3
    int nodeo = tilebase + (lane >> 2);
    if (nodeo < N)
        *(uint4*)(hout8 + (size_t)nodeo * 64 + (size_t)(lane & 3) * 16) = hv4;
}

// ---------------- decoder + softmax + residual (proven standalone) ----------------

__global__ __launch_bounds__(256, 4) void decoder_kernel(
    const unsigned char* __restrict__ h8, const float* __restrict__ x,
    const float* __restrict__ dw1, const float* __restrict__ db1,
    const float* __restrict__ dw2, const float* __restrict__ db2,
    float* __restrict__ out, int N) {
    int lane = threadIdx.x & 63;
    int wid = __builtin_amdgcn_readfirstlane((blockIdx.x * blockDim.x + threadIdx.x) >> 6);
    int n0 = wid * 4;
    if (n0 >= N) return;

    float w1col[DEMB];
    #pragma unroll
    for (int k = 0; k < DEMB; k++) w1col[k] = dw1[k * DEMB + lane];
    float db1v = db1[lane];
    float w20 = dw2[lane * 2], w21 = dw2[lane * 2 + 1];
    float db20 = db2[0], db21 = db2[1];

    float xv = 0.0f;
    if (lane < 8 && n0 * 2 + lane < 2 * N) xv = x[n0 * 2 + lane];

    float myout = 0.0f;
    #pragma unroll
    for (int m = 0; m < 4; m++) {
        int node = n0 + m;
        if (node >= N) continue;
        float hv = __builtin_amdgcn_cvt_f32_fp8((int)h8[(size_t)node * 64 + lane], 0);
        float y = db1v;
        #pragma unroll
        for (int k = 0; k < DEMB; k++)
            y = fmaf(rdlane(hv, k), w1col[k], y);
        float d1 = fmaxf(y, 0.0f);
        float p0 = d1 * w20, p1 = d1 * w21;
        #pragma unroll
        for (int off = 32; off > 0; off >>= 1) {
            p0 += __shfl_xor(p0, off);
            p1 += __shfl_xor(p1, off);
        }
        float o0 = p0 + db20, o1 = p1 + db21;
        float mm = fmaxf(o0, o1);
        float e0 = __expf(o0 - mm), e1 = __expf(o1 - mm);
        float inv = 1.0f / (e0 + e1);
        float r0 = e0 * inv + 2.0f * rdlane(xv, 2 * m);   // wc = [2, 0]
        float r1 = e1 * inv;
        if (lane == 2 * m) myout = r0;
        if (lane == 2 * m + 1) myout = r1;
    }
    if (lane < 8 && n0 * 2 + lane < 2 * N)
        out[n0 * 2 + lane] = myout;
}

// ---------------- launch ----------------

extern "C" void kernel_launch(void* const* d_in, const int* in_sizes, int n_in,
                              void* d_out, int out_size, void* d_ws, size_t ws_size,
                              hipStream_t stream) {
    const float* x      = (const float*)d_in[0];
    const int*   ei     = (const int*)d_in[1];
    const float* ew     = (const float*)d_in[2];
    const float* enc_w1 = (const float*)d_in[3];
    const float* enc_b1 = (const float*)d_in[4];
    const float* enc_w2 = (const float*)d_in[5];
    const float* enc_b2 = (const float*)d_in[6];
    const float* gcn_w  = (const float*)d_in[7];
    const float* gcn_b  = (const float*)d_in[8];
    const float* dec_w1 = (const float*)d_in[9];
    const float* dec_b1 = (const float*)d_in[10];
    const float* dec_w2 = (const float*)d_in[11];
    const float* dec_b2 = (const float*)d_in[12];
    float* out = (float*)d_out;

    const int N = in_sizes[0] / 2;
    const int E = in_sizes[2];
    const int L = in_sizes[7] / (DEMB * DEMB);
    const int NBKT = (N + NPBKT - 1) / NPBKT;
    const int NWG = (E + CHUNK - 1) / CHUNK;

    size_t padcap = (size_t)E + (size_t)NWG * NBKT * 7 + 64;          // cells
    size_t csrcap = padcap + (size_t)NBKT * NPBKT * 8;                // + row pads

    // workspace layout (256B aligned); h rows 64 B fp8
    char* ws = (char*)d_ws;
    size_t o = 0;
    auto alignup = [](size_t v) { return (v + 255) & ~(size_t)255; };
    unsigned int* hA = (unsigned int*)(ws + o); o = alignup(o + (size_t)N * DEMB);
    unsigned int* hB = (unsigned int*)(ws + o); o = alignup(o + (size_t)N * DEMB);
    float* dis     = (float*)(ws + o); o = alignup(o + (size_t)N * 4);
    int2*  rowse   = (int2*)(ws + o);  o = alignup(o + (size_t)N * 8);
    int*   histM   = (int*)(ws + o);   o = alignup(o + (size_t)NWG * NBKT * 4);
    int*   bktcnt  = (int*)(ws + o);   o = alignup(o + (size_t)MAXBKT * 4);
    int*   bktbase = (int*)(ws + o);   o = alignup(o + (size_t)(MAXBKT + 1) * 4);
    size_t cells_bytes = padcap * 8;
    int2*  cells   = (int2*)(ws + o);  o = alignup(o + cells_bytes);
    int2*  csr     = (int2*)(ws + o);  o = alignup(o + csrcap * 8);

    const int TB = 256;
    dim3 blk(TB);
    dim3 gWave4((N * 16 + TB - 1) / TB);          // wave per 4 nodes (enc/dec)
    dim3 gFused((N + 63) / 64);                   // 64 nodes per 256-thread block

    histA_kernel<<<NWG, blk, 0, stream>>>(ei, histM, E, NBKT);
    scanM_kernel<<<NBKT, blk, 0, stream>>>(histM, bktcnt, NWG, NBKT);
    scanB_kernel<<<1, 512, 0, stream>>>(bktcnt, bktbase, NBKT);
    binA_kernel<<<NWG, blk, 0, stream>>>(ei, ew, histM, bktbase, cells, E, NBKT);
    bucketB_kernel<<<NBKT, blk, 0, stream>>>(cells, bktbase, csr, rowse, dis, N);

    encoder_kernel<<<gWave4, blk, 0, stream>>>(x, dis, enc_w1, enc_b1, enc_w2, enc_b2, hA, N);

    unsigned int* hin = hA;
    unsigned int* hout = hB;
    for (int l = 0; l < L; l++) {
        const float* Wl = gcn_w + (size_t)l * DEMB * DEMB;
        const float* bl = gcn_b + (size_t)l * DEMB;
        if (l < L - 1) {
            fused_layer_kernel<1><<<gFused, blk, 0, stream>>>(
                (const uint4*)hin, csr, rowse, dis, Wl, bl,
                (unsigned char*)hout, N);
        } else {
            fused_layer_kernel<0><<<gFused, blk, 0, stream>>>(
                (const uint4*)hin, csr, rowse, dis, Wl, bl,
                (unsigned char*)hout, N);
        }
        unsigned int* tp = hin; hin = hout; hout = tp;
    }

    decoder_kernel<<<gWave4, blk, 0, stream>>>((const unsigned char*)hin, x,
                                               dec_w1, dec_b1, dec_w2, dec_b2, out, N);
}

// Round 5
// 315.568 us; speedup vs baseline: 1.6017x; 1.1634x over previous
//
#include <hip/hip_runtime.h>
#include <hip/hip_bf16.h>
#include <math.h>

#define DEMB 64
#define NPBKT 256          // nodes per coarse bucket (c >> 8)
#define CHUNK 4096         // edges per binning workgroup
#define MAXBKT 512
#define SENT_CAP 7168      // LDS staging entries in pass B (57 KB)

typedef float v2f __attribute__((ext_vector_type(2)));
typedef short short8 __attribute__((ext_vector_type(8)));
typedef float f32x4 __attribute__((ext_vector_type(4)));

// ---------------- helpers ----------------

__device__ __forceinline__ float rdlane(float v, int k) {
    return __int_as_float(__builtin_amdgcn_readlane(__float_as_int(v), k));
}
__device__ __forceinline__ unsigned int f2bf(float f) {
    union { float f; unsigned int i; } c; c.f = f;
    unsigned int r = c.i + 0x7FFFu + ((c.i >> 16) & 1u);   // RNE
    return r >> 16;
}

// pack 64 lanes' y (feature=lane) into fp8 row; lanes 0..15 store one dword each
__device__ __forceinline__ void pack_store_fp8(float y, unsigned int* __restrict__ dst, int lane) {
    float y0 = __shfl(y, 4 * lane + 0);
    float y1 = __shfl(y, 4 * lane + 1);
    float y2 = __shfl(y, 4 * lane + 2);
    float y3 = __shfl(y, 4 * lane + 3);
    int u = __builtin_amdgcn_cvt_pk_fp8_f32(y0, y1, 0, false);
    u = __builtin_amdgcn_cvt_pk_fp8_f32(y2, y3, u, true);
    if (lane < 16) dst[lane] = (unsigned int)u;
}

// ---------------- preprocessing: zero-atomic exact-base counting sort ----------------

__global__ __launch_bounds__(256) void histA_kernel(const int* __restrict__ ei,
                                                    int* __restrict__ histM,
                                                    int E, int NBKT) {
    __shared__ int lh[MAXBKT];
    int t = threadIdx.x;
    for (int b = t; b < MAXBKT; b += 256) lh[b] = 0;
    __syncthreads();
    int base = blockIdx.x * CHUNK;
    int end = base + CHUNK; if (end > E) end = E;
    for (int i = base + t; i < end; i += 256)
        atomicAdd(&lh[((unsigned int)ei[E + i]) >> 8], 1);
    __syncthreads();
    for (int b = t; b < NBKT; b += 256) {
        int c = lh[b];
        histM[(size_t)blockIdx.x * NBKT + b] = c ? ((c + 7) & ~7) : 0;
    }
}

__global__ __launch_bounds__(256) void scanM_kernel(int* __restrict__ histM,
                                                    int* __restrict__ bktcnt,
                                                    int NWG, int NBKT) {
    int b = blockIdx.x;
    int t = threadIdx.x, lane = t & 63, w = t >> 6;
    int w0 = 2 * t, w1 = 2 * t + 1;
    int v0 = (w0 < NWG) ? histM[(size_t)w0 * NBKT + b] : 0;
    int v1 = (w1 < NWG) ? histM[(size_t)w1 * NBKT + b] : 0;
    int s = v0 + v1;
    int sc = s;
    #pragma unroll
    for (int off = 1; off < 64; off <<= 1) {
        int u = __shfl_up(sc, off);
        if (lane >= off) sc += u;
    }
    __shared__ int wt[4];
    if (lane == 63) wt[w] = sc;
    __syncthreads();
    int woff = 0;
    for (int i = 0; i < w; i++) woff += wt[i];
    int ex = woff + sc - s;
    if (w0 < NWG) histM[(size_t)w0 * NBKT + b] = ex;
    if (w1 < NWG) histM[(size_t)w1 * NBKT + b] = ex + v0;
    if (t == 0) bktcnt[b] = wt[0] + wt[1] + wt[2] + wt[3];
}

__global__ void scanB_kernel(const int* __restrict__ bktcnt, int* __restrict__ bktbase,
                             int NBKT) {
    __shared__ int sh[512];
    int t = threadIdx.x;
    int mine = (t < NBKT) ? bktcnt[t] : 0;
    sh[t] = mine;
    __syncthreads();
    for (int off = 1; off < 512; off <<= 1) {
        int v = (t >= off) ? sh[t - off] : 0;
        __syncthreads();
        sh[t] += v;
        __syncthreads();
    }
    if (t < NBKT) bktbase[t] = sh[t] - mine;
    if (t == 511) bktbase[NBKT] = sh[511];
}

// entry: x = (c&255)<<20 | r  (valid x >= 0), sentinel pad x = -1
__global__ __launch_bounds__(256) void binA_kernel(const int* __restrict__ ei,
                                                   const float* __restrict__ ew,
                                                   const int* __restrict__ histM,
                                                   const int* __restrict__ bktbase,
                                                   int2* __restrict__ cells,
                                                   int E, int NBKT) {
    __shared__ int lh[MAXBKT];
    __shared__ int lbs[MAXBKT];
    __shared__ int lcur[MAXBKT];
    int t = threadIdx.x;
    for (int b = t; b < MAXBKT; b += 256) { lh[b] = 0; lcur[b] = 0; }
    __syncthreads();
    int base = blockIdx.x * CHUNK;
    int end = base + CHUNK; if (end > E) end = E;

    int cc[CHUNK / 256];
    int nloc = 0;
    for (int i = base + t; i < end; i += 256, nloc++) {
        int c = ei[E + i];
        cc[nloc] = c;
        atomicAdd(&lh[((unsigned int)c) >> 8], 1);
    }
    __syncthreads();
    for (int b = t; b < NBKT; b += 256)
        lbs[b] = bktbase[b] + histM[(size_t)blockIdx.x * NBKT + b];
    __syncthreads();
    int k = 0;
    for (int i = base + t; i < end; i += 256, k++) {
        unsigned int c = (unsigned int)cc[k];
        unsigned int r = (unsigned int)ei[i];
        int wbits = __float_as_int(ew[i]);
        int bkt = c >> 8;
        int rel = atomicAdd(&lcur[bkt], 1);
        cells[lbs[bkt] + rel] = make_int2((int)(((c & 255u) << 20) | r), wbits);
    }
    __syncthreads();
    for (int b = t; b < NBKT; b += 256) {
        int cnt = lh[b];
        if (cnt) {
            int pc = (cnt + 7) & ~7;
            for (int j = cnt; j < pc; j++)
                cells[lbs[b] + j] = make_int2(-1, 0);
        }
    }
}

// pass B: per bucket — count + weighted degree (skip sentinels), padded scan,
// write dis/rowse, sort into LDS. Rows padded to (cnt+8)&~7: the FIRST pad slot is
// (self, w=1.0) — the self-loop term — remaining pads are (self, 0).
__global__ __launch_bounds__(256) void bucketB_kernel(
    const int2* __restrict__ cells, const int* __restrict__ bktbase,
    int2* __restrict__ csr, int2* __restrict__ rowse, float* __restrict__ dis, int N) {
    __shared__ int scnt[NPBKT];
    __shared__ float sdeg[NPBKT];
    __shared__ int sstart[NPBKT];
    __shared__ int sfill[NPBKT];
    __shared__ int ssc[NPBKT];
    __shared__ int2 sout[SENT_CAP];

    int b = blockIdx.x;
    int t = threadIdx.x;
    int nodebase = b << 8;
    int nNodes = N - nodebase; if (nNodes > NPBKT) nNodes = NPBKT;

    if (t < NPBKT) { scnt[t] = 0; sdeg[t] = 1.0f; sfill[t] = 0; }   // self-loop deg=1
    __syncthreads();

    int lo = bktbase[b], hi = bktbase[b + 1];
    int outbase = lo + b * (NPBKT * 8);     // room for row pads (<=8/node), disjoint

    for (int i = lo + t; i < hi; i += 256) {
        int2 en = cells[i];
        if (en.x >= 0) {
            unsigned int ld = ((unsigned int)en.x) >> 20;
            atomicAdd(&scnt[ld], 1);
            atomicAdd(&sdeg[ld], __int_as_float(en.y));
        }
    }
    __syncthreads();

    int cnt_t = scnt[t];
    int pc_t = (cnt_t + 8) & ~7;            // padded row length (includes self slot)
    ssc[t] = pc_t;
    __syncthreads();
    for (int off = 1; off < NPBKT; off <<= 1) {
        int v = (t >= off) ? ssc[t - off] : 0;
        __syncthreads();
        ssc[t] += v;
        __syncthreads();
    }
    sstart[t] = ssc[t] - pc_t;
    __syncthreads();
    int ptotal = ssc[NPBKT - 1];

    if (t < nNodes) {
        int node = nodebase + t;
        dis[node] = rsqrtf(sdeg[t]);
        rowse[node] = make_int2(outbase + sstart[t], outbase + sstart[t] + pc_t);
    }

    if (ptotal <= SENT_CAP) {
        for (int i = lo + t; i < hi; i += 256) {
            int2 en = cells[i];
            if (en.x >= 0) {
                unsigned int ux = (unsigned int)en.x;
                unsigned int ld = ux >> 20;
                int pos = sstart[ld] + atomicAdd(&sfill[ld], 1);
                sout[pos] = make_int2((int)(ux & 0xFFFFFu), en.y);
            }
        }
        __syncthreads();
        if (t < nNodes) {
            for (int j = cnt_t; j < pc_t; j++)
                sout[sstart[t] + j] =
                    make_int2(nodebase + t, (j == cnt_t) ? 0x3f800000 : 0);
        }
        __syncthreads();
        for (int i = t; i < ptotal; i += 256)
            csr[outbase + i] = sout[i];
    } else {
        // pathological-skew fallback: direct global scatter
        for (int i = lo + t; i < hi; i += 256) {
            int2 en = cells[i];
            if (en.x >= 0) {
                unsigned int ux = (unsigned int)en.x;
                unsigned int ld = ux >> 20;
                int pos = atomicAdd(&sfill[ld], 1);
                csr[outbase + sstart[ld] + pos] = make_int2((int)(ux & 0xFFFFFu), en.y);
            }
        }
        __syncthreads();
        if (t < nNodes) {
            for (int j = cnt_t; j < pc_t; j++)
                csr[outbase + sstart[t] + j] =
                    make_int2(nodebase + t, (j == cnt_t) ? 0x3f800000 : 0);
        }
    }
}

// ---------------- encoder: stores s = dis * h_enc as fp8 ----------------

__global__ __launch_bounds__(256, 4) void encoder_kernel(
    const float* __restrict__ x, const float* __restrict__ dis,
    const float* __restrict__ w1, const float* __restrict__ b1,
    const float* __restrict__ w2, const float* __restrict__ b2,
    unsigned int* __restrict__ hout4, int N) {
    int lane = threadIdx.x & 63;
    int wid = __builtin_amdgcn_readfirstlane((blockIdx.x * blockDim.x + threadIdx.x) >> 6);
    int n0 = wid * 4;
    if (n0 >= N) return;

    float w2col[DEMB];
    #pragma unroll
    for (int k = 0; k < DEMB; k++) w2col[k] = w2[k * DEMB + lane];
    float w1a = w1[lane], w1b = w1[DEMB + lane];
    float b1v = b1[lane], b2v = b2[lane];

    float xv = 0.0f;
    if (lane < 8 && n0 * 2 + lane < 2 * N) xv = x[n0 * 2 + lane];

    #pragma unroll
    for (int m = 0; m < 4; m++) {
        int node = n0 + m;
        if (node >= N) continue;
        float x0 = rdlane(xv, 2 * m);
        float x1 = rdlane(xv, 2 * m + 1);
        float t = fmaxf(0.0f, fmaf(x0, w1a, fmaf(x1, w1b, b1v)));
        float y = b2v;
        #pragma unroll
        for (int k = 0; k < DEMB; k++)
            y = fmaf(rdlane(t, k), w2col[k], y);
        pack_store_fp8(y * dis[node], hout4 + (size_t)node * 16, lane);
    }
}

// ------- fused layer, wave16: one wave owns 16 nodes (4 lanes/node, 16B chunk/lane).
// No cross-lane reduction (lanes own disjoint features). Self term comes from CSR
// (first pad slot w=1). Per block: 4 waves = 64 nodes; W preloaded once (8 KB LDS,
// one barrier), then waves fully independent.
// Agg loop: 4 slots/node/iter, csr prefetched 2 groups (8 slots) ahead, and the
// whole group is exec-mask skipped once a node's row is done (mylen%8==0 makes
// `it < mylen` uniform over the node's 4 lanes and its group of 4 slots).

__device__ __forceinline__ void agg_acc8(v2f* __restrict__ acc, uint4 u, float w) {
    v2f wv = {w, w};
    acc[0] += wv * __builtin_amdgcn_cvt_pk_f32_fp8((int)u.x, false);
    acc[1] += wv * __builtin_amdgcn_cvt_pk_f32_fp8((int)u.x, true);
    acc[2] += wv * __builtin_amdgcn_cvt_pk_f32_fp8((int)u.y, false);
    acc[3] += wv * __builtin_amdgcn_cvt_pk_f32_fp8((int)u.y, true);
    acc[4] += wv * __builtin_amdgcn_cvt_pk_f32_fp8((int)u.z, false);
    acc[5] += wv * __builtin_amdgcn_cvt_pk_f32_fp8((int)u.z, true);
    acc[6] += wv * __builtin_amdgcn_cvt_pk_f32_fp8((int)u.w, false);
    acc[7] += wv * __builtin_amdgcn_cvt_pk_f32_fp8((int)u.w, true);
}

template<int SCALE>
__global__ __launch_bounds__(256, 6) void fused_layer_kernel(
    const uint4* __restrict__ hin4, const int2* __restrict__ csr,
    const int2* __restrict__ rowse, const float* __restrict__ dis,
    const float* __restrict__ W, const float* __restrict__ bias,
    unsigned char* __restrict__ hout8, int N) {

    __shared__ short Wl[8][64][8];     // B-fragments [nt*2+kt][quad*16+col][j], 8 KB
    __shared__ uint4 Gl4[4][128];      // per-wave 16 x 128 B bf16 G tile, 8 KB

    int t = threadIdx.x;
    int lane = t & 63;
    int wl = __builtin_amdgcn_readfirstlane(t >> 6);   // 0..3
    int tilebase = blockIdx.x * 64 + wl * 16;

    // ---- W preload (coalesced reads, scattered 2B LDS stores); only barrier ----
    #pragma unroll
    for (int rr = 0; rr < 16; rr++) {
        int li = rr * 256 + t;                         // linear index into W
        int r = li >> 6, c = li & 63;
        int nt = c >> 4, col = c & 15, kt = r >> 5, quad = (r >> 3) & 3, j = r & 7;
        Wl[nt * 2 + kt][quad * 16 + col][j] = (short)f2bf(W[li]);
    }
    __syncthreads();
    if (tilebase >= N) return;

    // ---- phase 1: aggregation; lane = nd*4+sub, nd=node 0..15, sub=16B chunk ----
    int nd = lane >> 2, sub = lane & 3;
    int node = tilebase + nd;
    bool vn = node < N;
    int cn = vn ? node : N - 1;

    int2 se = rowse[cn];
    int sx = se.x;
    int mylen = vn ? (se.y - sx) : 0;       // multiple of 8, >= 8 for valid nodes
    int lim = mylen > 0 ? mylen - 1 : 0;    // clamp target for prefetch addresses
    int maxlen = mylen;
    #pragma unroll
    for (int off = 4; off <= 32; off <<= 1)
        maxlen = max(maxlen, __shfl_xor(maxlen, off));

    v2f acc[8];
    #pragma unroll
    for (int k = 0; k < 8; k++) acc[k] = (v2f){0.0f, 0.0f};

    // prologue: load groups 0 and 1 (8 slots), clamped (rows are >= 8 when valid)
    int2 c0 = csr[sx + min(0, lim)], c1 = csr[sx + min(1, lim)];
    int2 c2 = csr[sx + min(2, lim)], c3 = csr[sx + min(3, lim)];
    int2 n0 = csr[sx + min(4, lim)], n1 = csr[sx + min(5, lim)];
    int2 n2 = csr[sx + min(6, lim)], n3 = csr[sx + min(7, lim)];

    for (int it = 0; it < maxlen; it += 4) {
        // prefetch group it+8 (exec-masked: finished / short rows issue nothing)
        int b = it + 8;
        int2 p0, p1, p2, p3;
        if (b < mylen) {
            p0 = csr[sx + b];     p1 = csr[sx + b + 1];
            p2 = csr[sx + b + 2]; p3 = csr[sx + b + 3];
        } else { p0 = c0; p1 = c0; p2 = c0; p3 = c0; }
        // process current group (uniform predicate per node: mylen % 8 == 0)
        if (it < mylen) {
            uint4 u0 = hin4[(size_t)c0.x * 4 + sub];
            uint4 u1 = hin4[(size_t)c1.x * 4 + sub];
            uint4 u2 = hin4[(size_t)c2.x * 4 + sub];
            uint4 u3 = hin4[(size_t)c3.x * 4 + sub];
            agg_acc8(acc, u0, __int_as_float(c0.y));
            agg_acc8(acc, u1, __int_as_float(c1.y));
            agg_acc8(acc, u2, __int_as_float(c2.y));
            agg_acc8(acc, u3, __int_as_float(c3.y));
        }
        c0 = n0; c1 = n1; c2 = n2; c3 = n3;
        n0 = p0; n1 = p1; n2 = p2; n3 = p3;
    }

    // G row = dis_c * acc  (self term already included via w=1 pad slot)
    float d = dis[cn];
    v2f dvp = {d, d};
    #pragma unroll
    for (int k = 0; k < 8; k++) acc[k] *= dvp;

    // ---- phase 2: bf16 G tile (per-wave LDS region, XOR-swizzled rows) ----
    char* gw = (char*)(&Gl4[wl][0]);
    {
        uint4 g0, g1;
        g0.x = f2bf(acc[0].x) | (f2bf(acc[0].y) << 16);
        g0.y = f2bf(acc[1].x) | (f2bf(acc[1].y) << 16);
        g0.z = f2bf(acc[2].x) | (f2bf(acc[2].y) << 16);
        g0.w = f2bf(acc[3].x) | (f2bf(acc[3].y) << 16);
        g1.x = f2bf(acc[4].x) | (f2bf(acc[4].y) << 16);
        g1.y = f2bf(acc[5].x) | (f2bf(acc[5].y) << 16);
        g1.z = f2bf(acc[6].x) | (f2bf(acc[6].y) << 16);
        g1.w = f2bf(acc[7].x) | (f2bf(acc[7].y) << 16);
        int swz = (nd & 7) << 4;
        *(uint4*)(gw + nd * 128 + ((sub * 32) ^ swz)) = g0;       // feats sub*16..+7
        *(uint4*)(gw + nd * 128 + ((sub * 32 + 16) ^ swz)) = g1;  // feats sub*16+8..+15
    }

    // ---- phase 3: 8 MFMA; all 16 C rows are our 16 nodes ----
    int col = lane & 15, quad = lane >> 4;
    int rsw = (col & 7) << 4;
    short8 Af0 = *(const short8*)(gw + col * 128 + ((quad * 16) ^ rsw));
    short8 Af1 = *(const short8*)(gw + col * 128 + ((64 + quad * 16) ^ rsw));

    float dvv = dis[min(tilebase + col, N - 1)];   // lane c (c<16) holds dis[tile+c]

    f32x4 z[4];
    #pragma unroll
    for (int nt = 0; nt < 4; nt++) {
        short8 B0 = *(const short8*)(&Wl[nt * 2 + 0][lane][0]);
        short8 B1 = *(const short8*)(&Wl[nt * 2 + 1][lane][0]);
        f32x4 zz = {0.0f, 0.0f, 0.0f, 0.0f};
        zz = __builtin_amdgcn_mfma_f32_16x16x32_bf16(Af0, B0, zz, 0, 0, 0);
        zz = __builtin_amdgcn_mfma_f32_16x16x32_bf16(Af1, B1, zz, 0, 0, 0);
        z[nt] = zz;
    }

    // ---- phase 4: epilogue  h' = relu(z + b) (* dis if SCALE) -> fp8 rows ----
    // byte tile reuses gw (same-wave DS ops are in-order; Af already in registers)
    #pragma unroll
    for (int nt = 0; nt < 4; nt++) {
        float bv = bias[nt * 16 + col];
        #pragma unroll
        for (int reg = 0; reg < 4; reg++) {
            int nr = quad * 4 + reg;                   // node-local row 0..15
            float os = SCALE ? rdlane(dvv, nr) : 1.0f;
            float y = fmaxf(z[nt][reg] + bv, 0.0f) * os;
            int u = __builtin_amdgcn_cvt_pk_fp8_f32(y, y, 0, false);
            gw[nr * 64 + nt * 16 + col] = (unsigned char)(u & 0xff);
        }
    }
    uint4 hv4 = *(const uint4*)(gw + lane * 16);       // row lane>>2, chunk lane&3
    int nodeo = tilebase + (lane >> 2);
    if (nodeo < N)
        *(uint4*)(hout8 + (size_t)nodeo * 64 + (size_t)(lane & 3) * 16) = hv4;
}

// ---------------- decoder + softmax + residual (proven standalone) ----------------

__global__ __launch_bounds__(256, 4) void decoder_kernel(
    const unsigned char* __restrict__ h8, const float* __restrict__ x,
    const float* __restrict__ dw1, const float* __restrict__ db1,
    const float* __restrict__ dw2, const float* __restrict__ db2,
    float* __restrict__ out, int N) {
    int lane = threadIdx.x & 63;
    int wid = __builtin_amdgcn_readfirstlane((blockIdx.x * blockDim.x + threadIdx.x) >> 6);
    int n0 = wid * 4;
    if (n0 >= N) return;

    float w1col[DEMB];
    #pragma unroll
    for (int k = 0; k < DEMB; k++) w1col[k] = dw1[k * DEMB + lane];
    float db1v = db1[lane];
    float w20 = dw2[lane * 2], w21 = dw2[lane * 2 + 1];
    float db20 = db2[0], db21 = db2[1];

    float xv = 0.0f;
    if (lane < 8 && n0 * 2 + lane < 2 * N) xv = x[n0 * 2 + lane];

    float myout = 0.0f;
    #pragma unroll
    for (int m = 0; m < 4; m++) {
        int node = n0 + m;
        if (node >= N) continue;
        float hv = __builtin_amdgcn_cvt_f32_fp8((int)h8[(size_t)node * 64 + lane], 0);
        float y = db1v;
        #pragma unroll
        for (int k = 0; k < DEMB; k++)
            y = fmaf(rdlane(hv, k), w1col[k], y);
        float d1 = fmaxf(y, 0.0f);
        float p0 = d1 * w20, p1 = d1 * w21;
        #pragma unroll
        for (int off = 32; off > 0; off >>= 1) {
            p0 += __shfl_xor(p0, off);
            p1 += __shfl_xor(p1, off);
        }
        float o0 = p0 + db20, o1 = p1 + db21;
        float mm = fmaxf(o0, o1);
        float e0 = __expf(o0 - mm), e1 = __expf(o1 - mm);
        float inv = 1.0f / (e0 + e1);
        float r0 = e0 * inv + 2.0f * rdlane(xv, 2 * m);   // wc = [2, 0]
        float r1 = e1 * inv;
        if (lane == 2 * m) myout = r0;
        if (lane == 2 * m + 1) myout = r1;
    }
    if (lane < 8 && n0 * 2 + lane < 2 * N)
        out[n0 * 2 + lane] = myout;
}

// ---------------- launch ----------------

extern "C" void kernel_launch(void* const* d_in, const int* in_sizes, int n_in,
                              void* d_out, int out_size, void* d_ws, size_t ws_size,
                              hipStream_t stream) {
    const float* x      = (const float*)d_in[0];
    const int*   ei     = (const int*)d_in[1];
    const float* ew     = (const float*)d_in[2];
    const float* enc_w1 = (const float*)d_in[3];
    const float* enc_b1 = (const float*)d_in[4];
    const float* enc_w2 = (const float*)d_in[5];
    const float* enc_b2 = (const float*)d_in[6];
    const float* gcn_w  = (const float*)d_in[7];
    const float* gcn_b  = (const float*)d_in[8];
    const float* dec_w1 = (const float*)d_in[9];
    const float* dec_b1 = (const float*)d_in[10];
    const float* dec_w2 = (const float*)d_in[11];
    const float* dec_b2 = (const float*)d_in[12];
    float* out = (float*)d_out;

    const int N = in_sizes[0] / 2;
    const int E = in_sizes[2];
    const int L = in_sizes[7] / (DEMB * DEMB);
    const int NBKT = (N + NPBKT - 1) / NPBKT;
    const int NWG = (E + CHUNK - 1) / CHUNK;

    size_t padcap = (size_t)E + (size_t)NWG * NBKT * 7 + 64;          // cells
    size_t csrcap = padcap + (size_t)NBKT * NPBKT * 8;                // + row pads

    // workspace layout (256B aligned); h rows 64 B fp8
    char* ws = (char*)d_ws;
    size_t o = 0;
    auto alignup = [](size_t v) { return (v + 255) & ~(size_t)255; };
    unsigned int* hA = (unsigned int*)(ws + o); o = alignup(o + (size_t)N * DEMB);
    unsigned int* hB = (unsigned int*)(ws + o); o = alignup(o + (size_t)N * DEMB);
    float* dis     = (float*)(ws + o); o = alignup(o + (size_t)N * 4);
    int2*  rowse   = (int2*)(ws + o);  o = alignup(o + (size_t)N * 8);
    int*   histM   = (int*)(ws + o);   o = alignup(o + (size_t)NWG * NBKT * 4);
    int*   bktcnt  = (int*)(ws + o);   o = alignup(o + (size_t)MAXBKT * 4);
    int*   bktbase = (int*)(ws + o);   o = alignup(o + (size_t)(MAXBKT + 1) * 4);
    size_t cells_bytes = padcap * 8;
    int2*  cells   = (int2*)(ws + o);  o = alignup(o + cells_bytes);
    int2*  csr     = (int2*)(ws + o);  o = alignup(o + csrcap * 8);

    const int TB = 256;
    dim3 blk(TB);
    dim3 gWave4((N * 16 + TB - 1) / TB);          // wave per 4 nodes (enc/dec)
    dim3 gFused((N + 63) / 64);                   // 64 nodes per 256-thread block

    histA_kernel<<<NWG, blk, 0, stream>>>(ei, histM, E, NBKT);
    scanM_kernel<<<NBKT, blk, 0, stream>>>(histM, bktcnt, NWG, NBKT);
    scanB_kernel<<<1, 512, 0, stream>>>(bktcnt, bktbase, NBKT);
    binA_kernel<<<NWG, blk, 0, stream>>>(ei, ew, histM, bktbase, cells, E, NBKT);
    bucketB_kernel<<<NBKT, blk, 0, stream>>>(cells, bktbase, csr, rowse, dis, N);

    encoder_kernel<<<gWave4, blk, 0, stream>>>(x, dis, enc_w1, enc_b1, enc_w2, enc_b2, hA, N);

    unsigned int* hin = hA;
    unsigned int* hout = hB;
    for (int l = 0; l < L; l++) {
        const float* Wl = gcn_w + (size_t)l * DEMB * DEMB;
        const float* bl = gcn_b + (size_t)l * DEMB;
        if (l < L - 1) {
            fused_layer_kernel<1><<<gFused, blk, 0, stream>>>(
                (const uint4*)hin, csr, rowse, dis, Wl, bl,
                (unsigned char*)hout, N);
        } else {
            fused_layer_kernel<0><<<gFused, blk, 0, stream>>>(
                (const uint4*)hin, csr, rowse, dis, Wl, bl,
                (unsigned char*)hout, N);
        }
        unsigned int* tp = hin; hin = hout; hout = tp;
    }

    decoder_kernel<<<gWave4, blk, 0, stream>>>((const unsigned char*)hin, x,
                                               dec_w1, dec_b1, dec_w2, dec_b2, out, N);
}